// Round 1
// baseline (4748.946 us; speedup 1.0000x reference)
//
#include <hip/hip_runtime.h>
#include <hip/hip_bf16.h>

#define WS_B 32
#define WS_T 64
#define WS_S 64
#define WS_D 512

// ---------------------------------------------------------------- helpers
__device__ __forceinline__ unsigned f2bf1(float x) {
    union { float f; unsigned u; } c; c.f = x;
    return (c.u + 0x7fffu + ((c.u >> 16) & 1u)) >> 16;   // RNE
}
__device__ __forceinline__ uint2 pack4bf(float4 v) {
    uint2 r;
    r.x = f2bf1(v.x) | (f2bf1(v.y) << 16);
    r.y = f2bf1(v.z) | (f2bf1(v.w) << 16);
    return r;
}
__device__ __forceinline__ float4 bf4_to_f4(const unsigned short* p) {
    uint2 u = *(const uint2*)p;
    float4 r;
    r.x = __uint_as_float(u.x << 16);
    r.y = __uint_as_float(u.x & 0xffff0000u);
    r.z = __uint_as_float(u.y << 16);
    r.w = __uint_as_float(u.y & 0xffff0000u);
    return r;
}

// ---------------------------------------------------------------- GEMM
// C[r, n] = act( A[r,:] . W[n,:] + bias[n] ) (+ resid[r,n])
// A: (R x K) lda, W: (N x K) ldw row-major, C: (R x N) ldc. Tiles 64x64x16.
__global__ __launch_bounds__(256) void gemm_kernel(
    const float* __restrict__ A, int lda,
    const float* __restrict__ W, int ldw,
    const float* __restrict__ bias,
    const float* __restrict__ resid,
    float* __restrict__ C, int ldc,
    int K, int relu)
{
    __shared__ float As[16][64];
    __shared__ float Ws[16][64];
    const int tid = threadIdx.x;
    const int tx = tid & 15, ty = tid >> 4;
    const int rowT = blockIdx.y * 64, colT = blockIdx.x * 64;
    const int lr = tid >> 2;           // 0..63
    const int lk = (tid & 3) << 2;     // 0,4,8,12
    const float* Ap = A + (long)(rowT + lr) * lda + lk;
    const float* Wp = W + (long)(colT + lr) * ldw + lk;

    float acc[4][4];
#pragma unroll
    for (int i = 0; i < 4; ++i)
#pragma unroll
        for (int j = 0; j < 4; ++j) acc[i][j] = 0.f;

    for (int k0 = 0; k0 < K; k0 += 16) {
        float4 av = *(const float4*)(Ap + k0);
        float4 wv = *(const float4*)(Wp + k0);
        __syncthreads();
        As[lk + 0][lr] = av.x; As[lk + 1][lr] = av.y;
        As[lk + 2][lr] = av.z; As[lk + 3][lr] = av.w;
        Ws[lk + 0][lr] = wv.x; Ws[lk + 1][lr] = wv.y;
        Ws[lk + 2][lr] = wv.z; Ws[lk + 3][lr] = wv.w;
        __syncthreads();
#pragma unroll
        for (int kk = 0; kk < 16; ++kk) {
            float4 a = *(const float4*)&As[kk][ty * 4];
            float4 w = *(const float4*)&Ws[kk][tx * 4];
            float aa[4] = {a.x, a.y, a.z, a.w};
            float ww[4] = {w.x, w.y, w.z, w.w};
#pragma unroll
            for (int i = 0; i < 4; ++i)
#pragma unroll
                for (int j = 0; j < 4; ++j) acc[i][j] += aa[i] * ww[j];
        }
    }

    const int col = colT + tx * 4;
    float4 bv;
    if (bias) bv = *(const float4*)(bias + col);
    else { bv.x = bv.y = bv.z = bv.w = 0.f; }
#pragma unroll
    for (int i = 0; i < 4; ++i) {
        const int grow = rowT + ty * 4 + i;
        float4 v;
        v.x = acc[i][0] + bv.x; v.y = acc[i][1] + bv.y;
        v.z = acc[i][2] + bv.z; v.w = acc[i][3] + bv.w;
        if (relu) {
            v.x = fmaxf(v.x, 0.f); v.y = fmaxf(v.y, 0.f);
            v.z = fmaxf(v.z, 0.f); v.w = fmaxf(v.w, 0.f);
        }
        if (resid) {
            float4 rv = *(const float4*)(resid + (long)grow * ldc + col);
            v.x += rv.x; v.y += rv.y; v.z += rv.z; v.w += rv.w;
        }
        *(float4*)(C + (long)grow * ldc + col) = v;
    }
}

// ---------------------------------------------------------------- fused rel
// One block per (t,b) pair: r = t*B + b.
// h1[s,d] = relu(F[r,d] + Smat[b*S+s,d])           (F includes +b0)
// h2[s,i] = relu(h1[s,:] . w1[i,:] + b1[i])
// score[s] = h2[s,:] . w2   -> softmax over s -> rel[r,:] = sum_s a[s]*sem[b,s,:]
__global__ __launch_bounds__(256) void rel_kernel(
    const float* __restrict__ F,
    const float* __restrict__ Smat,
    const float* __restrict__ sem,
    const float* __restrict__ w1,
    const float* __restrict__ b1,
    const float* __restrict__ w2,
    float* __restrict__ rel)
{
    __shared__ uint2 ldsb[8192];               // 64 KB, aliased across phases
    unsigned short* h1s = (unsigned short*)ldsb;   // [64][512] bf16
    const int tid = threadIdx.x;
    const int r = blockIdx.x;
    const int b = r & (WS_B - 1);

    // phase 1: build h1 (bf16) in LDS
    for (int idx = tid; idx < WS_S * 128; idx += 256) {
        const int s = idx >> 7;
        const int dq = (idx & 127) << 2;
        float4 f = *(const float4*)(F + (long)r * WS_D + dq);
        float4 sm = *(const float4*)(Smat + (long)(b * WS_S + s) * WS_D + dq);
        float4 h;
        h.x = fmaxf(f.x + sm.x, 0.f); h.y = fmaxf(f.y + sm.y, 0.f);
        h.z = fmaxf(f.z + sm.z, 0.f); h.w = fmaxf(f.w + sm.w, 0.f);
        *(uint2*)(h1s + s * WS_D + dq) = pack4bf(h);
    }
    __syncthreads();

    // phase 2: h2 = relu(h1 @ w1^T + b1); partial scores
    const int tx = tid & 15, ty = tid >> 4;
    const int s0 = ty * 4;
    float sp[4] = {0.f, 0.f, 0.f, 0.f};
    for (int chunk = 0; chunk < 8; ++chunk) {
        const int i0 = chunk * 64 + tx * 4;
        float acc[4][4];
#pragma unroll
        for (int i = 0; i < 4; ++i)
#pragma unroll
            for (int j = 0; j < 4; ++j) acc[i][j] = 0.f;
        const float* wr0 = w1 + (long)(i0 + 0) * WS_D;
        const float* wr1 = w1 + (long)(i0 + 1) * WS_D;
        const float* wr2 = w1 + (long)(i0 + 2) * WS_D;
        const float* wr3 = w1 + (long)(i0 + 3) * WS_D;
        for (int k = 0; k < WS_D; k += 4) {
            float4 a0 = bf4_to_f4(h1s + (s0 + 0) * WS_D + k);
            float4 a1 = bf4_to_f4(h1s + (s0 + 1) * WS_D + k);
            float4 a2 = bf4_to_f4(h1s + (s0 + 2) * WS_D + k);
            float4 a3 = bf4_to_f4(h1s + (s0 + 3) * WS_D + k);
            float4 w0 = *(const float4*)(wr0 + k);
            float4 w1v = *(const float4*)(wr1 + k);
            float4 w2v = *(const float4*)(wr2 + k);
            float4 w3 = *(const float4*)(wr3 + k);
            float4 aa[4] = {a0, a1, a2, a3};
            float4 wwv[4] = {w0, w1v, w2v, w3};
#pragma unroll
            for (int i = 0; i < 4; ++i)
#pragma unroll
                for (int j = 0; j < 4; ++j) {
                    acc[i][j] += aa[i].x * wwv[j].x + aa[i].y * wwv[j].y
                               + aa[i].z * wwv[j].z + aa[i].w * wwv[j].w;
                }
        }
#pragma unroll
        for (int j = 0; j < 4; ++j) {
            const float b1v = b1[i0 + j];
            const float w2s = w2[i0 + j];
#pragma unroll
            for (int i = 0; i < 4; ++i)
                sp[i] += fmaxf(acc[i][j] + b1v, 0.f) * w2s;
        }
    }
    __syncthreads();   // h1s now dead; reuse LDS

    float* sc = (float*)ldsb;         // [16][64]
#pragma unroll
    for (int i = 0; i < 4; ++i) sc[tx * 64 + s0 + i] = sp[i];
    __syncthreads();

    float* a_s = ((float*)ldsb) + 1024;   // [64] softmax weights
    if (tid < 64) {
        float t = 0.f;
#pragma unroll
        for (int q = 0; q < 16; ++q) t += sc[q * 64 + tid];
        float m = t;
#pragma unroll
        for (int off = 32; off > 0; off >>= 1) m = fmaxf(m, __shfl_xor(m, off));
        float e = __expf(t - m);
        float su = e;
#pragma unroll
        for (int off = 32; off > 0; off >>= 1) su += __shfl_xor(su, off);
        a_s[tid] = e / su;
    }
    __syncthreads();

    // phase 4: rel[r,:] = sum_s a[s] * sem[b,s,:]
    for (int d = tid; d < WS_D; d += 256) {
        float accd = 0.f;
        for (int s = 0; s < WS_S; ++s)
            accd += a_s[s] * sem[(long)(b * WS_S + s) * WS_D + d];
        rel[(long)r * WS_D + d] = accd;
    }
}

// ---------------------------------------------------------------- attention
// One block per (b,h). Lq fixed 64, head dim 64, B=32.
// Row layouts: X[(seq*B + b)*ld + h*64 + d].
__global__ __launch_bounds__(256) void attn_kernel(
    const float* __restrict__ Q, int ldq,
    const float* __restrict__ K, int ldk,
    const float* __restrict__ V, int ldv,
    float* __restrict__ O, int ldo,
    int Lk)
{
    extern __shared__ float sS[];    // [Lk][64] k-major
    const int tid = threadIdx.x;
    const int b = blockIdx.x >> 3;
    const int h = blockIdx.x & 7;
    const float* Qb = Q + (long)b * ldq + h * 64;
    const float* Kb = K + (long)b * ldk + h * 64;
    const float* Vb = V + (long)b * ldv + h * 64;
    float* Ob = O + (long)b * ldo + h * 64;

    for (int idx = tid; idx < 64 * Lk; idx += 256) {
        const int q = idx & 63, k = idx >> 6;
        const float4* qp = (const float4*)(Qb + (long)q * WS_B * ldq);
        const float4* kp = (const float4*)(Kb + (long)k * WS_B * ldk);
        float acc = 0.f;
#pragma unroll
        for (int d = 0; d < 16; ++d) {
            float4 a = qp[d], c = kp[d];
            acc += a.x * c.x + a.y * c.y + a.z * c.z + a.w * c.w;
        }
        sS[k * 64 + q] = acc * 0.125f;   // 1/sqrt(64)
    }
    __syncthreads();

    if (tid < 64) {
        const int q = tid;
        float m = -1e30f;
        for (int k = 0; k < Lk; ++k) m = fmaxf(m, sS[k * 64 + q]);
        float su = 0.f;
        for (int k = 0; k < Lk; ++k) {
            float e = __expf(sS[k * 64 + q] - m);
            sS[k * 64 + q] = e;
            su += e;
        }
        const float inv = 1.f / su;
        for (int k = 0; k < Lk; ++k) sS[k * 64 + q] *= inv;
    }
    __syncthreads();

    for (int idx = tid; idx < 64 * 64; idx += 256) {
        const int d = idx & 63, q = idx >> 6;
        float acc = 0.f;
        for (int k = 0; k < Lk; ++k)
            acc += sS[k * 64 + q] * Vb[(long)k * WS_B * ldv + d];
        Ob[(long)q * WS_B * ldo + d] = acc;
    }
}

// ---------------------------------------------------------------- layernorm
// One wave per row of 512. grid = rows/4, block 256.
__global__ __launch_bounds__(256) void ln_kernel(
    const float* __restrict__ X,
    const float* __restrict__ g,
    const float* __restrict__ be,
    float* __restrict__ Y)
{
    const int row = blockIdx.x * 4 + (threadIdx.x >> 6);
    const int lane = threadIdx.x & 63;
    const float4* xp = (const float4*)(X + (long)row * WS_D);
    float4 x0 = xp[lane], x1 = xp[lane + 64];
    float sum = x0.x + x0.y + x0.z + x0.w + x1.x + x1.y + x1.z + x1.w;
    float sq = x0.x * x0.x + x0.y * x0.y + x0.z * x0.z + x0.w * x0.w
             + x1.x * x1.x + x1.y * x1.y + x1.z * x1.z + x1.w * x1.w;
#pragma unroll
    for (int off = 32; off > 0; off >>= 1) {
        sum += __shfl_xor(sum, off);
        sq += __shfl_xor(sq, off);
    }
    const float mu = sum * (1.f / 512.f);
    const float var = sq * (1.f / 512.f) - mu * mu;
    const float rs = rsqrtf(var + 1e-5f);
    const float4* gp = (const float4*)g;
    const float4* bp = (const float4*)be;
    float4 g0 = gp[lane], g1 = gp[lane + 64], b0 = bp[lane], b1 = bp[lane + 64];
    float4 y0, y1;
    y0.x = (x0.x - mu) * rs * g0.x + b0.x;
    y0.y = (x0.y - mu) * rs * g0.y + b0.y;
    y0.z = (x0.z - mu) * rs * g0.z + b0.z;
    y0.w = (x0.w - mu) * rs * g0.w + b0.w;
    y1.x = (x1.x - mu) * rs * g1.x + b1.x;
    y1.y = (x1.y - mu) * rs * g1.y + b1.y;
    y1.z = (x1.z - mu) * rs * g1.z + b1.z;
    y1.w = (x1.w - mu) * rs * g1.w + b1.w;
    float4* yp = (float4*)(Y + (long)row * WS_D);
    yp[lane] = y0; yp[lane + 64] = y1;
}

// ---------------------------------------------------------------- launch
static inline void gemm(hipStream_t s, const float* A, int lda,
                        const float* W, int ldw,
                        const float* bias, const float* resid,
                        float* C, int ldc, int R, int N, int K, bool relu)
{
    dim3 g(N / 64, R / 64);
    gemm_kernel<<<g, 256, 0, s>>>(A, lda, W, ldw, bias, resid, C, ldc, K, relu ? 1 : 0);
}

extern "C" void kernel_launch(void* const* d_in, const int* in_sizes, int n_in,
                              void* d_out, int out_size, void* d_ws, size_t ws_size,
                              hipStream_t stream)
{
    (void)in_sizes; (void)n_in; (void)out_size; (void)ws_size;
    const float* tgt       = (const float*)d_in[0];
    const float* memory    = (const float*)d_in[1];
    const float* semantics = (const float*)d_in[2];
    const float* pt_wqkv   = (const float*)d_in[3];
    const float* pt_bqkv   = (const float*)d_in[4];
    const float* pt_wo     = (const float*)d_in[5];
    const float* pt_bo     = (const float*)d_in[6];
    const float* sa_wqkv   = (const float*)d_in[7];
    const float* sa_bqkv   = (const float*)d_in[8];
    const float* sa_wo     = (const float*)d_in[9];
    const float* sa_bo     = (const float*)d_in[10];
    const float* ca_wqkv   = (const float*)d_in[11];
    const float* ca_bqkv   = (const float*)d_in[12];
    const float* ca_wo     = (const float*)d_in[13];
    const float* ca_bo     = (const float*)d_in[14];
    const float* mlp_w0    = (const float*)d_in[15];
    const float* mlp_b0    = (const float*)d_in[16];
    const float* mlp_w1    = (const float*)d_in[17];
    const float* mlp_b1    = (const float*)d_in[18];
    const float* mlp_w2    = (const float*)d_in[19];
    /* mlp_b2 (d_in[20]) is a constant added to every softmax logit -> no-op */
    const float* ffn_w1    = (const float*)d_in[21];
    const float* ffn_b1    = (const float*)d_in[22];
    const float* ffn_w2    = (const float*)d_in[23];
    const float* ffn_b2    = (const float*)d_in[24];
    const float* ln1_g     = (const float*)d_in[25];
    const float* ln1_b     = (const float*)d_in[26];
    const float* ln2_g     = (const float*)d_in[27];
    const float* ln2_b     = (const float*)d_in[28];
    const float* ln3_g     = (const float*)d_in[29];
    const float* ln3_b     = (const float*)d_in[30];

    float* ws = (float*)d_ws;
    const long M1 = 1 << 20;
    float* F    = ws;            // (2048,512) rows t*B+b, includes +b0
    float* Smat = ws + 1 * M1;   // (2048,512) rows b*S+s
    float* rel  = ws + 2 * M1;   // (2048,512) rows t*B+b  == sem_k layout
    float* b4   = ws + 3 * M1;   // (2048,512) Q / pre-LN
    float* b5   = ws + 4 * M1;   // (2048,512) attention output
    float* b6   = ws + 5 * M1;   // (2048,512) running x
    float* b3   = ws + 6 * M1;   // big: up to (8192,1024) / (2048,2048)

    // rel = get_relevant_semantic(...)
    gemm(stream, tgt, 512, mlp_w0, 1024, mlp_b0, nullptr, F, 512, 2048, 512, 512, false);
    gemm(stream, semantics, 512, mlp_w0 + 512, 1024, nullptr, nullptr, Smat, 512, 2048, 512, 512, false);
    rel_kernel<<<2048, 256, 0, stream>>>(F, Smat, semantics, mlp_w1, mlp_b1, mlp_w2, rel);

    // pt attention: q=tgt, k=v=rel (sem_k), Lk=64; x = tgt + out
    gemm(stream, tgt, 512, pt_wqkv, 512, pt_bqkv, nullptr, b4, 512, 2048, 512, 512, false);
    gemm(stream, rel, 512, pt_wqkv + 512 * 512, 512, pt_bqkv + 512, nullptr, b3, 1024, 2048, 1024, 512, false);
    attn_kernel<<<256, 256, 64 * 64 * 4, stream>>>(b4, 512, b3, 1024, b3 + 512, 1024, b5, 512, 64);
    gemm(stream, b5, 512, pt_wo, 512, pt_bo, tgt, b6, 512, 2048, 512, 512, false);

    // self attention + ln1
    gemm(stream, b6, 512, sa_wqkv, 512, sa_bqkv, nullptr, b3, 1536, 2048, 1536, 512, false);
    attn_kernel<<<256, 256, 64 * 64 * 4, stream>>>(b3, 1536, b3 + 512, 1536, b3 + 1024, 1536, b5, 512, 64);
    gemm(stream, b5, 512, sa_wo, 512, sa_bo, b6, b4, 512, 2048, 512, 512, false);
    ln_kernel<<<512, 256, 0, stream>>>(b4, ln1_g, ln1_b, b6);

    // cross attention (memory, Lk=256) + ln2
    gemm(stream, b6, 512, ca_wqkv, 512, ca_bqkv, nullptr, b4, 512, 2048, 512, 512, false);
    gemm(stream, memory, 512, ca_wqkv + 512 * 512, 512, ca_bqkv + 512, nullptr, b3, 1024, 8192, 1024, 512, false);
    attn_kernel<<<256, 256, 64 * 256 * 4, stream>>>(b4, 512, b3, 1024, b3 + 512, 1024, b5, 512, 256);
    gemm(stream, b5, 512, ca_wo, 512, ca_bo, b6, F, 512, 2048, 512, 512, false);
    ln_kernel<<<512, 256, 0, stream>>>(F, ln2_g, ln2_b, b6);

    // FFN + ln3 -> out
    gemm(stream, b6, 512, ffn_w1, 512, ffn_b1, nullptr, b3, 2048, 2048, 2048, 512, true);
    gemm(stream, b3, 2048, ffn_w2, 2048, ffn_b2, b6, F, 512, 2048, 512, 2048, false);
    ln_kernel<<<512, 256, 0, stream>>>(F, ln3_g, ln3_b, (float*)d_out);
}

// Round 2
// 1270.531 us; speedup vs baseline: 3.7378x; 3.7378x over previous
//
#include <hip/hip_runtime.h>
#include <hip/hip_bf16.h>

#define WS_B 32
#define WS_T 64
#define WS_S 64
#define WS_D 512

typedef __attribute__((ext_vector_type(8))) __bf16 bf16x8;
typedef __attribute__((ext_vector_type(4))) float f32x4;
typedef unsigned short ushort_t;

// ---------------------------------------------------------------- helpers
__device__ __forceinline__ unsigned packpair(float lo, float hi) {
    // round-half-up bf16 pack of two floats into one u32 (lo in low half)
    return ((__float_as_uint(lo) + 0x8000u) >> 16) |
           ((__float_as_uint(hi) + 0x8000u) & 0xffff0000u);
}
// lo/hi bf16 halves of word f + word s, add, relu, repack
__device__ __forceinline__ unsigned fuse_word(unsigned f, unsigned s) {
    float lo = __uint_as_float(f << 16) + __uint_as_float(s << 16);
    float hi = __uint_as_float(f & 0xffff0000u) + __uint_as_float(s & 0xffff0000u);
    lo = fmaxf(lo, 0.f);
    hi = fmaxf(hi, 0.f);
    return packpair(lo, hi);
}

// ---------------------------------------------------------------- GEMM (fp32)
// C[r, n] = act( A[r,:] . W[n,:] + bias[n] ) (+ resid[r,n]); obf -> bf16 out
__global__ __launch_bounds__(256) void gemm_kernel(
    const float* __restrict__ A, int lda,
    const float* __restrict__ W, int ldw,
    const float* __restrict__ bias,
    const float* __restrict__ resid,
    float* __restrict__ C, int ldc,
    int K, int relu, int obf)
{
    __shared__ float As[16][64];
    __shared__ float Ws[16][64];
    const int tid = threadIdx.x;
    const int tx = tid & 15, ty = tid >> 4;
    const int rowT = blockIdx.y * 64, colT = blockIdx.x * 64;
    const int lr = tid >> 2;           // 0..63
    const int lk = (tid & 3) << 2;     // 0,4,8,12
    const float* Ap = A + (long)(rowT + lr) * lda + lk;
    const float* Wp = W + (long)(colT + lr) * ldw + lk;

    float acc[4][4];
#pragma unroll
    for (int i = 0; i < 4; ++i)
#pragma unroll
        for (int j = 0; j < 4; ++j) acc[i][j] = 0.f;

    for (int k0 = 0; k0 < K; k0 += 16) {
        float4 av = *(const float4*)(Ap + k0);
        float4 wv = *(const float4*)(Wp + k0);
        __syncthreads();
        As[lk + 0][lr] = av.x; As[lk + 1][lr] = av.y;
        As[lk + 2][lr] = av.z; As[lk + 3][lr] = av.w;
        Ws[lk + 0][lr] = wv.x; Ws[lk + 1][lr] = wv.y;
        Ws[lk + 2][lr] = wv.z; Ws[lk + 3][lr] = wv.w;
        __syncthreads();
#pragma unroll
        for (int kk = 0; kk < 16; ++kk) {
            float4 a = *(const float4*)&As[kk][ty * 4];
            float4 w = *(const float4*)&Ws[kk][tx * 4];
            float aa[4] = {a.x, a.y, a.z, a.w};
            float ww[4] = {w.x, w.y, w.z, w.w};
#pragma unroll
            for (int i = 0; i < 4; ++i)
#pragma unroll
                for (int j = 0; j < 4; ++j) acc[i][j] += aa[i] * ww[j];
        }
    }

    const int col = colT + tx * 4;
    float4 bv;
    if (bias) bv = *(const float4*)(bias + col);
    else { bv.x = bv.y = bv.z = bv.w = 0.f; }
#pragma unroll
    for (int i = 0; i < 4; ++i) {
        const int grow = rowT + ty * 4 + i;
        float4 v;
        v.x = acc[i][0] + bv.x; v.y = acc[i][1] + bv.y;
        v.z = acc[i][2] + bv.z; v.w = acc[i][3] + bv.w;
        if (relu) {
            v.x = fmaxf(v.x, 0.f); v.y = fmaxf(v.y, 0.f);
            v.z = fmaxf(v.z, 0.f); v.w = fmaxf(v.w, 0.f);
        }
        if (resid) {
            float4 rv = *(const float4*)(resid + (long)grow * ldc + col);
            v.x += rv.x; v.y += rv.y; v.z += rv.z; v.w += rv.w;
        }
        if (obf) {
            ushort_t* Cb = (ushort_t*)C;
            uint2 o;
            o.x = packpair(v.x, v.y);
            o.y = packpair(v.z, v.w);
            *(uint2*)(Cb + (long)grow * ldc + col) = o;
        } else {
            *(float4*)(C + (long)grow * ldc + col) = v;
        }
    }
}

// ---------------------------------------------------------------- fp32 -> bf16
__global__ __launch_bounds__(256) void cvt_bf16_kernel(
    const float* __restrict__ X, ushort_t* __restrict__ Y, int n4)
{
    const int i = blockIdx.x * 256 + threadIdx.x;
    if (i < n4) {
        float4 v = ((const float4*)X)[i];
        uint2 o;
        o.x = packpair(v.x, v.y);
        o.y = packpair(v.z, v.w);
        ((uint2*)Y)[i] = o;
    }
}

// ---------------------------------------------------------------- h2 scores (MFMA)
// Rows m = r*64 + s (r = t*B+b). A[m,k] = relu(Fb[r,k] + Sb[b*64+s,k]) built
// on the fly. B = w1 (bf16, N x K row-major). Epilogue folds
// relu(acc + b1[col]) * w2[col], reduces over this block's 256 cols, writes
// scores4[nb][m] (nb = 0,1 column halves; summed in softrel).
__global__ __launch_bounds__(512, 2) void h2score_kernel(
    const ushort_t* __restrict__ Fb,   // (2048,512)
    const ushort_t* __restrict__ Sb,   // (2048,512) rows b*64+s
    const ushort_t* __restrict__ w1b,  // (512,512)
    const float* __restrict__ b1,
    const float* __restrict__ w2,
    float* __restrict__ scores4)       // (2, 131072)
{
    __shared__ ushort_t As[128 * 32];  // 8 KB
    __shared__ ushort_t Bs[256 * 32];  // 16 KB
    __shared__ float scred[128 * 4];   // 2 KB
    const int tid = threadIdx.x;
    const int mb = blockIdx.x, nb = blockIdx.y;
    const int w = tid >> 6, lane = tid & 63;
    const int wm = w & 1, wn = w >> 1;         // wave grid 2 (m) x 4 (n)
    const int l15 = lane & 15, quad = lane >> 4;

    // staging: each thread builds one 8-elem A chunk and two B chunks / k-step
    const int arow = tid >> 2, akc = tid & 3;
    const int m_g = mb * 128 + arow;
    const int r = m_g >> 6, s = m_g & 63, bidx = r & 31;
    const ushort_t* Fp = Fb + (long)r * 512 + akc * 8;
    const ushort_t* Sp = Sb + (long)(bidx * 64 + s) * 512 + akc * 8;
    const ushort_t* Bp0 = w1b + (long)(nb * 256 + (tid >> 2)) * 512 + (tid & 3) * 8;
    const ushort_t* Bp1 = Bp0 + (long)128 * 512;
    ushort_t* Asw = &As[arow * 32 + akc * 8];
    ushort_t* Bsw0 = &Bs[(tid >> 2) * 32 + (tid & 3) * 8];
    ushort_t* Bsw1 = Bsw0 + 128 * 32;

    f32x4 acc[4][4];
#pragma unroll
    for (int i = 0; i < 4; ++i)
#pragma unroll
        for (int j = 0; j < 4; ++j) acc[i][j] = (f32x4)0.f;

    for (int k0 = 0; k0 < 512; k0 += 32) {
        uint4 fa = *(const uint4*)(Fp + k0);
        uint4 sa = *(const uint4*)(Sp + k0);
        uint4 bb0 = *(const uint4*)(Bp0 + k0);
        uint4 bb1 = *(const uint4*)(Bp1 + k0);
        __syncthreads();
        uint4 o;
        o.x = fuse_word(fa.x, sa.x);
        o.y = fuse_word(fa.y, sa.y);
        o.z = fuse_word(fa.z, sa.z);
        o.w = fuse_word(fa.w, sa.w);
        *(uint4*)Asw = o;
        *(uint4*)Bsw0 = bb0;
        *(uint4*)Bsw1 = bb1;
        __syncthreads();
        bf16x8 af[4], bf[4];
#pragma unroll
        for (int mt = 0; mt < 4; ++mt)
            af[mt] = *(const bf16x8*)&As[(wm * 64 + mt * 16 + l15) * 32 + quad * 8];
#pragma unroll
        for (int nt = 0; nt < 4; ++nt)
            bf[nt] = *(const bf16x8*)&Bs[(wn * 64 + nt * 16 + l15) * 32 + quad * 8];
#pragma unroll
        for (int mt = 0; mt < 4; ++mt)
#pragma unroll
            for (int nt = 0; nt < 4; ++nt)
                acc[mt][nt] = __builtin_amdgcn_mfma_f32_16x16x32_bf16(
                    af[mt], bf[nt], acc[mt][nt], 0, 0, 0);
    }
    __syncthreads();   // all waves done with As/Bs before scred overlay writes

    // epilogue: score_part[row] = sum_cols relu(acc + b1) * w2
    float sp[4][4];
#pragma unroll
    for (int mt = 0; mt < 4; ++mt)
#pragma unroll
        for (int rg = 0; rg < 4; ++rg) sp[mt][rg] = 0.f;
#pragma unroll
    for (int nt = 0; nt < 4; ++nt) {
        const int col = nb * 256 + wn * 64 + nt * 16 + l15;
        const float cb = b1[col];
        const float cw = w2[col];
#pragma unroll
        for (int mt = 0; mt < 4; ++mt) {
#pragma unroll
            for (int rg = 0; rg < 4; ++rg)
                sp[mt][rg] += fmaxf(acc[mt][nt][rg] + cb, 0.f) * cw;
        }
    }
#pragma unroll
    for (int mt = 0; mt < 4; ++mt)
#pragma unroll
        for (int rg = 0; rg < 4; ++rg) {
            float v = sp[mt][rg];
            v += __shfl_xor(v, 1);
            v += __shfl_xor(v, 2);
            v += __shfl_xor(v, 4);
            v += __shfl_xor(v, 8);
            if (l15 == 0)
                scred[(wm * 64 + mt * 16 + quad * 4 + rg) * 4 + wn] = v;
        }
    __syncthreads();
    if (tid < 128) {
        float t = scred[tid * 4] + scred[tid * 4 + 1]
                + scred[tid * 4 + 2] + scred[tid * 4 + 3];
        scores4[(long)nb * 131072 + mb * 128 + tid] = t;
    }
}

// ---------------------------------------------------------------- softmax + weighted sum
__global__ __launch_bounds__(256) void softrel_kernel(
    const float* __restrict__ sc4,     // (2, 131072)
    const float* __restrict__ sem,     // (32, 64, 512) fp32
    float* __restrict__ rel)           // (2048, 512) rows r = t*B+b
{
    __shared__ float a_s[64];
    const int tid = threadIdx.x;
    const int r = blockIdx.x;
    const int b = r & (WS_B - 1);
    if (tid < 64) {
        float t = sc4[r * 64 + tid] + sc4[131072 + r * 64 + tid];
        float m = t;
#pragma unroll
        for (int off = 32; off > 0; off >>= 1) m = fmaxf(m, __shfl_xor(m, off));
        float e = __expf(t - m);
        float su = e;
#pragma unroll
        for (int off = 32; off > 0; off >>= 1) su += __shfl_xor(su, off);
        a_s[tid] = e / su;
    }
    __syncthreads();
#pragma unroll
    for (int dd = 0; dd < 2; ++dd) {
        const int d = tid + dd * 256;
        float accd = 0.f;
        const float* sp = sem + (long)b * 64 * 512 + d;
        for (int s = 0; s < 64; ++s)
            accd += a_s[s] * sp[s * 512];
        rel[(long)r * 512 + d] = accd;
    }
}

// ---------------------------------------------------------------- attention
__global__ __launch_bounds__(256) void attn_kernel(
    const float* __restrict__ Q, int ldq,
    const float* __restrict__ K, int ldk,
    const float* __restrict__ V, int ldv,
    float* __restrict__ O, int ldo,
    int Lk)
{
    extern __shared__ float sS[];    // [Lk][64] k-major
    const int tid = threadIdx.x;
    const int b = blockIdx.x >> 3;
    const int h = blockIdx.x & 7;
    const float* Qb = Q + (long)b * ldq + h * 64;
    const float* Kb = K + (long)b * ldk + h * 64;
    const float* Vb = V + (long)b * ldv + h * 64;
    float* Ob = O + (long)b * ldo + h * 64;

    for (int idx = tid; idx < 64 * Lk; idx += 256) {
        const int q = idx & 63, k = idx >> 6;
        const float4* qp = (const float4*)(Qb + (long)q * WS_B * ldq);
        const float4* kp = (const float4*)(Kb + (long)k * WS_B * ldk);
        float acc = 0.f;
#pragma unroll
        for (int d = 0; d < 16; ++d) {
            float4 a = qp[d], c = kp[d];
            acc += a.x * c.x + a.y * c.y + a.z * c.z + a.w * c.w;
        }
        sS[k * 64 + q] = acc * 0.125f;
    }
    __syncthreads();

    if (tid < 64) {
        const int q = tid;
        float m = -1e30f;
        for (int k = 0; k < Lk; ++k) m = fmaxf(m, sS[k * 64 + q]);
        float su = 0.f;
        for (int k = 0; k < Lk; ++k) {
            float e = __expf(sS[k * 64 + q] - m);
            sS[k * 64 + q] = e;
            su += e;
        }
        const float inv = 1.f / su;
        for (int k = 0; k < Lk; ++k) sS[k * 64 + q] *= inv;
    }
    __syncthreads();

    for (int idx = tid; idx < 64 * 64; idx += 256) {
        const int d = idx & 63, q = idx >> 6;
        float acc = 0.f;
        for (int k = 0; k < Lk; ++k)
            acc += sS[k * 64 + q] * Vb[(long)k * WS_B * ldv + d];
        Ob[(long)q * WS_B * ldo + d] = acc;
    }
}

// ---------------------------------------------------------------- layernorm
__global__ __launch_bounds__(256) void ln_kernel(
    const float* __restrict__ X,
    const float* __restrict__ g,
    const float* __restrict__ be,
    float* __restrict__ Y)
{
    const int row = blockIdx.x * 4 + (threadIdx.x >> 6);
    const int lane = threadIdx.x & 63;
    const float4* xp = (const float4*)(X + (long)row * WS_D);
    float4 x0 = xp[lane], x1 = xp[lane + 64];
    float sum = x0.x + x0.y + x0.z + x0.w + x1.x + x1.y + x1.z + x1.w;
    float sq = x0.x * x0.x + x0.y * x0.y + x0.z * x0.z + x0.w * x0.w
             + x1.x * x1.x + x1.y * x1.y + x1.z * x1.z + x1.w * x1.w;
#pragma unroll
    for (int off = 32; off > 0; off >>= 1) {
        sum += __shfl_xor(sum, off);
        sq += __shfl_xor(sq, off);
    }
    const float mu = sum * (1.f / 512.f);
    const float var = sq * (1.f / 512.f) - mu * mu;
    const float rs = rsqrtf(var + 1e-5f);
    const float4* gp = (const float4*)g;
    const float4* bp = (const float4*)be;
    float4 g0 = gp[lane], g1 = gp[lane + 64], b0 = bp[lane], b1 = bp[lane + 64];
    float4 y0, y1;
    y0.x = (x0.x - mu) * rs * g0.x + b0.x;
    y0.y = (x0.y - mu) * rs * g0.y + b0.y;
    y0.z = (x0.z - mu) * rs * g0.z + b0.z;
    y0.w = (x0.w - mu) * rs * g0.w + b0.w;
    y1.x = (x1.x - mu) * rs * g1.x + b1.x;
    y1.y = (x1.y - mu) * rs * g1.y + b1.y;
    y1.z = (x1.z - mu) * rs * g1.z + b1.z;
    y1.w = (x1.w - mu) * rs * g1.w + b1.w;
    float4* yp = (float4*)(Y + (long)row * WS_D);
    yp[lane] = y0; yp[lane + 64] = y1;
}

// ---------------------------------------------------------------- launch
static inline void gemm(hipStream_t s, const float* A, int lda,
                        const float* W, int ldw,
                        const float* bias, const float* resid,
                        float* C, int ldc, int R, int N, int K, bool relu,
                        int obf = 0)
{
    dim3 g(N / 64, R / 64);
    gemm_kernel<<<g, 256, 0, s>>>(A, lda, W, ldw, bias, resid, C, ldc, K,
                                  relu ? 1 : 0, obf);
}

extern "C" void kernel_launch(void* const* d_in, const int* in_sizes, int n_in,
                              void* d_out, int out_size, void* d_ws, size_t ws_size,
                              hipStream_t stream)
{
    (void)in_sizes; (void)n_in; (void)out_size; (void)ws_size;
    const float* tgt       = (const float*)d_in[0];
    const float* memory    = (const float*)d_in[1];
    const float* semantics = (const float*)d_in[2];
    const float* pt_wqkv   = (const float*)d_in[3];
    const float* pt_bqkv   = (const float*)d_in[4];
    const float* pt_wo     = (const float*)d_in[5];
    const float* pt_bo     = (const float*)d_in[6];
    const float* sa_wqkv   = (const float*)d_in[7];
    const float* sa_bqkv   = (const float*)d_in[8];
    const float* sa_wo     = (const float*)d_in[9];
    const float* sa_bo     = (const float*)d_in[10];
    const float* ca_wqkv   = (const float*)d_in[11];
    const float* ca_bqkv   = (const float*)d_in[12];
    const float* ca_wo     = (const float*)d_in[13];
    const float* ca_bo     = (const float*)d_in[14];
    const float* mlp_w0    = (const float*)d_in[15];
    const float* mlp_b0    = (const float*)d_in[16];
    const float* mlp_w1    = (const float*)d_in[17];
    const float* mlp_b1    = (const float*)d_in[18];
    const float* mlp_w2    = (const float*)d_in[19];
    /* mlp_b2 (d_in[20]) adds a constant to every softmax logit -> no-op */
    const float* ffn_w1    = (const float*)d_in[21];
    const float* ffn_b1    = (const float*)d_in[22];
    const float* ffn_w2    = (const float*)d_in[23];
    const float* ffn_b2    = (const float*)d_in[24];
    const float* ln1_g     = (const float*)d_in[25];
    const float* ln1_b     = (const float*)d_in[26];
    const float* ln2_g     = (const float*)d_in[27];
    const float* ln2_b     = (const float*)d_in[28];
    const float* ln3_g     = (const float*)d_in[29];
    const float* ln3_b     = (const float*)d_in[30];

    char* wsb = (char*)d_ws;
    ushort_t* Fb   = (ushort_t*)(wsb + (0L << 20));   // (2048,512) bf16, 2 MB
    ushort_t* Sb   = (ushort_t*)(wsb + (2L << 20));   // (2048,512) bf16, 2 MB
    ushort_t* w1b  = (ushort_t*)(wsb + (4L << 20));   // (512,512) bf16, 0.5 MB
    float* scores4 = (float*)(wsb + (5L << 20));      // (2,131072), 1 MB
    float* rel     = (float*)(wsb + (6L << 20));      // (2048,512) fp32, 4 MB
    float* b4      = (float*)(wsb + (10L << 20));
    float* b5      = (float*)(wsb + (14L << 20));
    float* b6      = (float*)(wsb + (18L << 20));
    float* b3      = (float*)(wsb + (22L << 20));     // 32 MB

    // ---- rel = get_relevant_semantic(...)  [MFMA path]
    cvt_bf16_kernel<<<256, 256, 0, stream>>>(mlp_w1, w1b, 65536);
    gemm(stream, tgt, 512, mlp_w0, 1024, mlp_b0, nullptr, (float*)Fb, 512, 2048, 512, 512, false, 1);
    gemm(stream, semantics, 512, mlp_w0 + 512, 1024, nullptr, nullptr, (float*)Sb, 512, 2048, 512, 512, false, 1);
    h2score_kernel<<<dim3(1024, 2), 512, 0, stream>>>(Fb, Sb, w1b, mlp_b1, mlp_w2, scores4);
    softrel_kernel<<<2048, 256, 0, stream>>>(scores4, semantics, rel);

    // ---- pt attention: q=tgt, k=v=rel (sem_k layout), Lk=64; x = tgt + out
    gemm(stream, tgt, 512, pt_wqkv, 512, pt_bqkv, nullptr, b4, 512, 2048, 512, 512, false);
    gemm(stream, rel, 512, pt_wqkv + 512 * 512, 512, pt_bqkv + 512, nullptr, b3, 1024, 2048, 1024, 512, false);
    attn_kernel<<<256, 256, 64 * 64 * 4, stream>>>(b4, 512, b3, 1024, b3 + 512, 1024, b5, 512, 64);
    gemm(stream, b5, 512, pt_wo, 512, pt_bo, tgt, b6, 512, 2048, 512, 512, false);

    // ---- self attention + ln1
    gemm(stream, b6, 512, sa_wqkv, 512, sa_bqkv, nullptr, b3, 1536, 2048, 1536, 512, false);
    attn_kernel<<<256, 256, 64 * 64 * 4, stream>>>(b3, 1536, b3 + 512, 1536, b3 + 1024, 1536, b5, 512, 64);
    gemm(stream, b5, 512, sa_wo, 512, sa_bo, b6, b4, 512, 2048, 512, 512, false);
    ln_kernel<<<512, 256, 0, stream>>>(b4, ln1_g, ln1_b, b6);

    // ---- cross attention (memory, Lk=256) + ln2
    gemm(stream, b6, 512, ca_wqkv, 512, ca_bqkv, nullptr, b4, 512, 2048, 512, 512, false);
    gemm(stream, memory, 512, ca_wqkv + 512 * 512, 512, ca_bqkv + 512, nullptr, b3, 1024, 8192, 1024, 512, false);
    attn_kernel<<<256, 256, 64 * 256 * 4, stream>>>(b4, 512, b3, 1024, b3 + 512, 1024, b5, 512, 256);
    gemm(stream, b5, 512, ca_wo, 512, ca_bo, b6, rel, 512, 2048, 512, 512, false);
    ln_kernel<<<512, 256, 0, stream>>>(rel, ln2_g, ln2_b, b6);

    // ---- FFN + ln3 -> out
    gemm(stream, b6, 512, ffn_w1, 512, ffn_b1, nullptr, b3, 2048, 2048, 2048, 512, true);
    gemm(stream, b3, 2048, ffn_w2, 2048, ffn_b2, b6, rel, 512, 2048, 512, 2048, false);
    ln_kernel<<<512, 256, 0, stream>>>(rel, ln3_g, ln3_b, (float*)d_out);
}

// Round 3
// 615.275 us; speedup vs baseline: 7.7184x; 2.0650x over previous
//
#include <hip/hip_runtime.h>
#include <hip/hip_bf16.h>

#define WS_B 32
#define WS_T 64
#define WS_S 64
#define WS_D 512

typedef __attribute__((ext_vector_type(8))) __bf16 bf16x8;
typedef __attribute__((ext_vector_type(4))) float f32x4;
typedef unsigned short ushort_t;

#define MB(x) ((size_t)(x) << 20)

// ---------------------------------------------------------------- helpers
__device__ __forceinline__ unsigned packpair(float lo, float hi) {
    return ((__float_as_uint(lo) + 0x8000u) >> 16) |
           ((__float_as_uint(hi) + 0x8000u) & 0xffff0000u);
}
__device__ __forceinline__ ushort_t f2bf(float x) {
    return (ushort_t)((__float_as_uint(x) + 0x8000u) >> 16);
}
__device__ __forceinline__ float bf2f(ushort_t u) {
    return __uint_as_float(((unsigned)u) << 16);
}
__device__ __forceinline__ unsigned fuse_word(unsigned f, unsigned s) {
    float lo = __uint_as_float(f << 16) + __uint_as_float(s << 16);
    float hi = __uint_as_float(f & 0xffff0000u) + __uint_as_float(s & 0xffff0000u);
    lo = fmaxf(lo, 0.f);
    hi = fmaxf(hi, 0.f);
    return packpair(lo, hi);
}

// ---------------------------------------------------------------- mega convert
struct CvtArgs {
    const float* src[13];
    ushort_t* dst[13];
    int n4[13];
};
__global__ __launch_bounds__(256) void megacvt_kernel(CvtArgs a) {
    const int t = blockIdx.y;
    const int n = a.n4[t];
    const float4* S = (const float4*)a.src[t];
    uint2* D = (uint2*)a.dst[t];
    for (int i = blockIdx.x * 256 + threadIdx.x; i < n; i += gridDim.x * 256) {
        float4 v = S[i];
        uint2 o;
        o.x = packpair(v.x, v.y);
        o.y = packpair(v.z, v.w);
        D[i] = o;
    }
}

// ---------------------------------------------------------------- MFMA GEMM
// C[m,n] = act(A[m,:] . W[n,:] + bias[n]) (+ resid[m,n])
// A bf16 (M x K, lda), W bf16 (N x K, ldw). Outputs: C fp32 and/or Cb bf16.
// Tile 128(M) x 256(N), 512 threads (8 waves, 2x4 wave grid, 64x64/wave).
__global__ __launch_bounds__(512, 2) void mfma_gemm(
    const ushort_t* __restrict__ A, int lda,
    const ushort_t* __restrict__ W, int ldw,
    const float* __restrict__ bias,
    const float* __restrict__ resid,
    float* __restrict__ C,
    ushort_t* __restrict__ Cb,
    int ldc, int K, int relu)
{
    __shared__ ushort_t As[128 * 32];
    __shared__ ushort_t Bs[256 * 32];
    const int tid = threadIdx.x;
    const int mb = blockIdx.y, nb = blockIdx.x;
    const int w = tid >> 6, lane = tid & 63;
    const int wm = w & 1, wn = w >> 1;
    const int l15 = lane & 15, quad = lane >> 4;
    const int arow = tid >> 2, akc = tid & 3;

    const ushort_t* Ap  = A + (long)(mb * 128 + arow) * lda + akc * 8;
    const ushort_t* Bp0 = W + (long)(nb * 256 + arow) * ldw + akc * 8;
    const ushort_t* Bp1 = Bp0 + (long)128 * ldw;
    ushort_t* Asw  = &As[arow * 32 + akc * 8];
    ushort_t* Bsw0 = &Bs[arow * 32 + akc * 8];
    ushort_t* Bsw1 = Bsw0 + 128 * 32;

    f32x4 acc[4][4];
#pragma unroll
    for (int i = 0; i < 4; ++i)
#pragma unroll
        for (int j = 0; j < 4; ++j) acc[i][j] = (f32x4)0.f;

    for (int k0 = 0; k0 < K; k0 += 32) {
        uint4 av  = *(const uint4*)(Ap + k0);
        uint4 bb0 = *(const uint4*)(Bp0 + k0);
        uint4 bb1 = *(const uint4*)(Bp1 + k0);
        __syncthreads();
        *(uint4*)Asw  = av;
        *(uint4*)Bsw0 = bb0;
        *(uint4*)Bsw1 = bb1;
        __syncthreads();
        bf16x8 af[4], bf[4];
#pragma unroll
        for (int mt = 0; mt < 4; ++mt)
            af[mt] = *(const bf16x8*)&As[(wm * 64 + mt * 16 + l15) * 32 + quad * 8];
#pragma unroll
        for (int nt = 0; nt < 4; ++nt)
            bf[nt] = *(const bf16x8*)&Bs[(wn * 64 + nt * 16 + l15) * 32 + quad * 8];
#pragma unroll
        for (int mt = 0; mt < 4; ++mt)
#pragma unroll
            for (int nt = 0; nt < 4; ++nt)
                acc[mt][nt] = __builtin_amdgcn_mfma_f32_16x16x32_bf16(
                    af[mt], bf[nt], acc[mt][nt], 0, 0, 0);
    }

#pragma unroll
    for (int nt = 0; nt < 4; ++nt) {
        const int col = nb * 256 + wn * 64 + nt * 16 + l15;
        const float bv = bias ? bias[col] : 0.f;
#pragma unroll
        for (int mt = 0; mt < 4; ++mt) {
            const int row0 = mb * 128 + wm * 64 + mt * 16 + quad * 4;
#pragma unroll
            for (int rg = 0; rg < 4; ++rg) {
                float v = acc[mt][nt][rg] + bv;
                if (relu) v = fmaxf(v, 0.f);
                const long off = (long)(row0 + rg) * ldc + col;
                if (resid) v += resid[off];
                if (C) C[off] = v;
                if (Cb) Cb[off] = f2bf(v);
            }
        }
    }
}

// ---------------------------------------------------------------- h2 scores (MFMA)
__global__ __launch_bounds__(512, 2) void h2score_kernel(
    const ushort_t* __restrict__ Fb,   // (2048,512)
    const ushort_t* __restrict__ Sb,   // (2048,512) rows b*64+s
    const ushort_t* __restrict__ w1b,  // (512,512)
    const float* __restrict__ b1,
    const float* __restrict__ w2,
    float* __restrict__ scores4)       // (2, 131072)
{
    __shared__ ushort_t As[128 * 32];
    __shared__ ushort_t Bs[256 * 32];
    __shared__ float scred[128 * 4];
    const int tid = threadIdx.x;
    const int mb = blockIdx.x, nb = blockIdx.y;
    const int w = tid >> 6, lane = tid & 63;
    const int wm = w & 1, wn = w >> 1;
    const int l15 = lane & 15, quad = lane >> 4;

    const int arow = tid >> 2, akc = tid & 3;
    const int m_g = mb * 128 + arow;
    const int r = m_g >> 6, s = m_g & 63, bidx = r & 31;
    const ushort_t* Fp = Fb + (long)r * 512 + akc * 8;
    const ushort_t* Sp = Sb + (long)(bidx * 64 + s) * 512 + akc * 8;
    const ushort_t* Bp0 = w1b + (long)(nb * 256 + (tid >> 2)) * 512 + (tid & 3) * 8;
    const ushort_t* Bp1 = Bp0 + (long)128 * 512;
    ushort_t* Asw = &As[arow * 32 + akc * 8];
    ushort_t* Bsw0 = &Bs[(tid >> 2) * 32 + (tid & 3) * 8];
    ushort_t* Bsw1 = Bsw0 + 128 * 32;

    f32x4 acc[4][4];
#pragma unroll
    for (int i = 0; i < 4; ++i)
#pragma unroll
        for (int j = 0; j < 4; ++j) acc[i][j] = (f32x4)0.f;

    for (int k0 = 0; k0 < 512; k0 += 32) {
        uint4 fa = *(const uint4*)(Fp + k0);
        uint4 sa = *(const uint4*)(Sp + k0);
        uint4 bb0 = *(const uint4*)(Bp0 + k0);
        uint4 bb1 = *(const uint4*)(Bp1 + k0);
        __syncthreads();
        uint4 o;
        o.x = fuse_word(fa.x, sa.x);
        o.y = fuse_word(fa.y, sa.y);
        o.z = fuse_word(fa.z, sa.z);
        o.w = fuse_word(fa.w, sa.w);
        *(uint4*)Asw = o;
        *(uint4*)Bsw0 = bb0;
        *(uint4*)Bsw1 = bb1;
        __syncthreads();
        bf16x8 af[4], bf[4];
#pragma unroll
        for (int mt = 0; mt < 4; ++mt)
            af[mt] = *(const bf16x8*)&As[(wm * 64 + mt * 16 + l15) * 32 + quad * 8];
#pragma unroll
        for (int nt = 0; nt < 4; ++nt)
            bf[nt] = *(const bf16x8*)&Bs[(wn * 64 + nt * 16 + l15) * 32 + quad * 8];
#pragma unroll
        for (int mt = 0; mt < 4; ++mt)
#pragma unroll
            for (int nt = 0; nt < 4; ++nt)
                acc[mt][nt] = __builtin_amdgcn_mfma_f32_16x16x32_bf16(
                    af[mt], bf[nt], acc[mt][nt], 0, 0, 0);
    }
    __syncthreads();

    float sp[4][4];
#pragma unroll
    for (int mt = 0; mt < 4; ++mt)
#pragma unroll
        for (int rg = 0; rg < 4; ++rg) sp[mt][rg] = 0.f;
#pragma unroll
    for (int nt = 0; nt < 4; ++nt) {
        const int col = nb * 256 + wn * 64 + nt * 16 + l15;
        const float cb = b1[col];
        const float cw = w2[col];
#pragma unroll
        for (int mt = 0; mt < 4; ++mt) {
#pragma unroll
            for (int rg = 0; rg < 4; ++rg)
                sp[mt][rg] += fmaxf(acc[mt][nt][rg] + cb, 0.f) * cw;
        }
    }
#pragma unroll
    for (int mt = 0; mt < 4; ++mt)
#pragma unroll
        for (int rg = 0; rg < 4; ++rg) {
            float v = sp[mt][rg];
            v += __shfl_xor(v, 1);
            v += __shfl_xor(v, 2);
            v += __shfl_xor(v, 4);
            v += __shfl_xor(v, 8);
            if (l15 == 0)
                scred[(wm * 64 + mt * 16 + quad * 4 + rg) * 4 + wn] = v;
        }
    __syncthreads();
    if (tid < 128) {
        float t = scred[tid * 4] + scred[tid * 4 + 1]
                + scred[tid * 4 + 2] + scred[tid * 4 + 3];
        scores4[(long)nb * 131072 + mb * 128 + tid] = t;
    }
}

// ---------------------------------------------------------------- softmax + weighted sum
__global__ __launch_bounds__(256) void softrel_kernel(
    const float* __restrict__ sc4,     // (2, 131072)
    const float* __restrict__ sem,     // (32, 64, 512) fp32
    ushort_t* __restrict__ rel)        // (2048, 512) bf16, rows r = t*B+b
{
    __shared__ float a_s[64];
    const int tid = threadIdx.x;
    const int r = blockIdx.x;
    const int b = r & (WS_B - 1);
    if (tid < 64) {
        float t = sc4[r * 64 + tid] + sc4[131072 + r * 64 + tid];
        float m = t;
#pragma unroll
        for (int off = 32; off > 0; off >>= 1) m = fmaxf(m, __shfl_xor(m, off));
        float e = __expf(t - m);
        float su = e;
#pragma unroll
        for (int off = 32; off > 0; off >>= 1) su += __shfl_xor(su, off);
        a_s[tid] = e / su;
    }
    __syncthreads();
#pragma unroll
    for (int dd = 0; dd < 2; ++dd) {
        const int d = tid + dd * 256;
        float accd = 0.f;
        const float* sp = sem + (long)b * 64 * 512 + d;
        for (int s = 0; s < 64; ++s)
            accd += a_s[s] * sp[s * 512];
        rel[(long)r * 512 + d] = f2bf(accd);
    }
}

// ---------------------------------------------------------------- attention v2
// bf16 row-major inputs: row (seq*32 + b)*ld + off + h*64 + d.
// Block = (b, h, q-half of 32). fp32 compute in LDS.
__global__ __launch_bounds__(256) void attn2_kernel(
    const ushort_t* __restrict__ Qm, int ldq, int qoff,
    const ushort_t* __restrict__ Km, int ldk, int koff,
    const ushort_t* __restrict__ Vm, int ldv, int voff,
    ushort_t* __restrict__ O,          // (2048,512) bf16
    int Lk)
{
    __shared__ float sQT[64 * 34];     // [d][q]   (32 q + pad)
    __shared__ float sKT[64 * 68];     // [d][k] tile; reused as sV[k][68]
    __shared__ float sS[32 * 260];     // [q][k]   (k up to 256 + pad)
    __shared__ float sredm[8 * 34];
    __shared__ float sreds[8 * 34];
    const int tid = threadIdx.x;
    const int b  = blockIdx.x >> 4;
    const int h  = (blockIdx.x >> 1) & 7;
    const int qt = blockIdx.x & 1;
    const int L8 = Lk >> 3;

    // stage Q (32 rows x 64 d) transposed
    {
        const int q = tid >> 3, c = tid & 7;
        const int qg = qt * 32 + q;
        const ushort_t* pp = Qm + (long)(qg * WS_B + b) * ldq + qoff + h * 64 + c * 8;
        uint4 u = *(const uint4*)pp;
        const ushort_t* us = (const ushort_t*)&u;
#pragma unroll
        for (int i = 0; i < 8; ++i)
            sQT[(c * 8 + i) * 34 + q] = bf2f(us[i]);
    }

    const int k4 = (tid & 15) * 4;
    const int q2 = (tid >> 4) * 2;

    // ---- S = Q K^T * scale
    for (int kt = 0; kt < Lk; kt += 64) {
        __syncthreads();
        {
            const int kk = tid >> 3, c = tid & 7;
#pragma unroll
            for (int half = 0; half < 2; ++half) {
                const int kr = kk + half * 32;
                const ushort_t* pp = Km + (long)((kt + kr) * WS_B + b) * ldk + koff + h * 64 + c * 8;
                uint4 u = *(const uint4*)pp;
                const ushort_t* us = (const ushort_t*)&u;
#pragma unroll
                for (int i = 0; i < 8; ++i)
                    sKT[(c * 8 + i) * 68 + kr] = bf2f(us[i]);
            }
        }
        __syncthreads();
        float acc[2][4] = {{0.f, 0.f, 0.f, 0.f}, {0.f, 0.f, 0.f, 0.f}};
        for (int d = 0; d < 64; ++d) {
            const float qa = sQT[d * 34 + q2];
            const float qb = sQT[d * 34 + q2 + 1];
            const float4 kv = *(const float4*)&sKT[d * 68 + k4];
            acc[0][0] += qa * kv.x; acc[0][1] += qa * kv.y;
            acc[0][2] += qa * kv.z; acc[0][3] += qa * kv.w;
            acc[1][0] += qb * kv.x; acc[1][1] += qb * kv.y;
            acc[1][2] += qb * kv.z; acc[1][3] += qb * kv.w;
        }
#pragma unroll
        for (int i = 0; i < 2; ++i) {
            float4 v;
            v.x = acc[i][0] * 0.125f; v.y = acc[i][1] * 0.125f;
            v.z = acc[i][2] * 0.125f; v.w = acc[i][3] * 0.125f;
            *(float4*)&sS[(q2 + i) * 260 + kt + k4] = v;
        }
    }
    __syncthreads();

    // ---- softmax (8 parts over k per q row); P left unnormalized
    {
        const int q = tid & 31, part = tid >> 5;
        const int kb = part * L8;
        float m = -1e30f;
        for (int k = 0; k < L8; ++k) m = fmaxf(m, sS[q * 260 + kb + k]);
        sredm[part * 34 + q] = m;
        __syncthreads();
        float M = sredm[q];
#pragma unroll
        for (int pz = 1; pz < 8; ++pz) M = fmaxf(M, sredm[pz * 34 + q]);
        float su = 0.f;
        for (int k = 0; k < L8; ++k) {
            float e = __expf(sS[q * 260 + kb + k] - M);
            sS[q * 260 + kb + k] = e;
            su += e;
        }
        sreds[part * 34 + q] = su;
    }
    __syncthreads();

    // ---- O = P V (accumulate unnormalized, scale by 1/sum at the end)
    const int d4 = (tid & 15) * 4;
    float o[2][4] = {{0.f, 0.f, 0.f, 0.f}, {0.f, 0.f, 0.f, 0.f}};
    float* sV = sKT;
    for (int kt = 0; kt < Lk; kt += 64) {
        __syncthreads();
        {
            const int kk = tid >> 3, c = tid & 7;
#pragma unroll
            for (int half = 0; half < 2; ++half) {
                const int kr = kk + half * 32;
                const ushort_t* pp = Vm + (long)((kt + kr) * WS_B + b) * ldv + voff + h * 64 + c * 8;
                uint4 u = *(const uint4*)pp;
                const ushort_t* us = (const ushort_t*)&u;
                float4 w0, w1;
                w0.x = bf2f(us[0]); w0.y = bf2f(us[1]);
                w0.z = bf2f(us[2]); w0.w = bf2f(us[3]);
                w1.x = bf2f(us[4]); w1.y = bf2f(us[5]);
                w1.z = bf2f(us[6]); w1.w = bf2f(us[7]);
                *(float4*)&sV[kr * 68 + c * 8] = w0;
                *(float4*)&sV[kr * 68 + c * 8 + 4] = w1;
            }
        }
        __syncthreads();
        for (int k = 0; k < 64; ++k) {
            const float p0 = sS[q2 * 260 + kt + k];
            const float p1 = sS[(q2 + 1) * 260 + kt + k];
            const float4 vv = *(const float4*)&sV[k * 68 + d4];
            o[0][0] += p0 * vv.x; o[0][1] += p0 * vv.y;
            o[0][2] += p0 * vv.z; o[0][3] += p0 * vv.w;
            o[1][0] += p1 * vv.x; o[1][1] += p1 * vv.y;
            o[1][2] += p1 * vv.z; o[1][3] += p1 * vv.w;
        }
    }

#pragma unroll
    for (int i = 0; i < 2; ++i) {
        float su = 0.f;
#pragma unroll
        for (int pz = 0; pz < 8; ++pz) su += sreds[pz * 34 + q2 + i];
        const float inv = 1.f / su;
        const int qg = qt * 32 + q2 + i;
        ushort_t* op = O + (long)(qg * WS_B + b) * 512 + h * 64 + d4;
        uint2 pk;
        pk.x = packpair(o[i][0] * inv, o[i][1] * inv);
        pk.y = packpair(o[i][2] * inv, o[i][3] * inv);
        *(uint2*)op = pk;
    }
}

// ---------------------------------------------------------------- layernorm (dual out)
__global__ __launch_bounds__(256) void ln_kernel(
    const float* __restrict__ X,
    const float* __restrict__ g,
    const float* __restrict__ be,
    float* __restrict__ Y,
    ushort_t* __restrict__ Yb)
{
    const int row = blockIdx.x * 4 + (threadIdx.x >> 6);
    const int lane = threadIdx.x & 63;
    const float4* xp = (const float4*)(X + (long)row * WS_D);
    float4 x0 = xp[lane], x1 = xp[lane + 64];
    float sum = x0.x + x0.y + x0.z + x0.w + x1.x + x1.y + x1.z + x1.w;
    float sq = x0.x * x0.x + x0.y * x0.y + x0.z * x0.z + x0.w * x0.w
             + x1.x * x1.x + x1.y * x1.y + x1.z * x1.z + x1.w * x1.w;
#pragma unroll
    for (int off = 32; off > 0; off >>= 1) {
        sum += __shfl_xor(sum, off);
        sq += __shfl_xor(sq, off);
    }
    const float mu = sum * (1.f / 512.f);
    const float var = sq * (1.f / 512.f) - mu * mu;
    const float rs = rsqrtf(var + 1e-5f);
    const float4* gp = (const float4*)g;
    const float4* bp = (const float4*)be;
    float4 g0 = gp[lane], g1 = gp[lane + 64], b0 = bp[lane], b1 = bp[lane + 64];
    float4 y0, y1;
    y0.x = (x0.x - mu) * rs * g0.x + b0.x;
    y0.y = (x0.y - mu) * rs * g0.y + b0.y;
    y0.z = (x0.z - mu) * rs * g0.z + b0.z;
    y0.w = (x0.w - mu) * rs * g0.w + b0.w;
    y1.x = (x1.x - mu) * rs * g1.x + b1.x;
    y1.y = (x1.y - mu) * rs * g1.y + b1.y;
    y1.z = (x1.z - mu) * rs * g1.z + b1.z;
    y1.w = (x1.w - mu) * rs * g1.w + b1.w;
    float4* yp = (float4*)(Y + (long)row * WS_D);
    yp[lane] = y0; yp[lane + 64] = y1;
    if (Yb) {
        uint2* ybp = (uint2*)(Yb + (long)row * WS_D);
        uint2 p0, p1;
        p0.x = packpair(y0.x, y0.y); p0.y = packpair(y0.z, y0.w);
        p1.x = packpair(y1.x, y1.y); p1.y = packpair(y1.z, y1.w);
        ybp[lane] = p0; ybp[lane + 64] = p1;
    }
}

// ---------------------------------------------------------------- launch
static inline void mgemm(hipStream_t s, const ushort_t* A, int lda,
                         const ushort_t* W, int ldw, const float* bias,
                         const float* resid, float* C, ushort_t* Cb,
                         int ldc, int M, int N, int K, bool relu)
{
    dim3 g(N / 256, M / 128);
    mfma_gemm<<<g, 512, 0, s>>>(A, lda, W, ldw, bias, resid, C, Cb, ldc, K,
                                relu ? 1 : 0);
}

extern "C" void kernel_launch(void* const* d_in, const int* in_sizes, int n_in,
                              void* d_out, int out_size, void* d_ws, size_t ws_size,
                              hipStream_t stream)
{
    (void)in_sizes; (void)n_in; (void)out_size; (void)ws_size;
    const float* tgt       = (const float*)d_in[0];
    const float* memory    = (const float*)d_in[1];
    const float* semantics = (const float*)d_in[2];
    const float* pt_wqkv   = (const float*)d_in[3];
    const float* pt_bqkv   = (const float*)d_in[4];
    const float* pt_wo     = (const float*)d_in[5];
    const float* pt_bo     = (const float*)d_in[6];
    const float* sa_wqkv   = (const float*)d_in[7];
    const float* sa_bqkv   = (const float*)d_in[8];
    const float* sa_wo     = (const float*)d_in[9];
    const float* sa_bo     = (const float*)d_in[10];
    const float* ca_wqkv   = (const float*)d_in[11];
    const float* ca_bqkv   = (const float*)d_in[12];
    const float* ca_wo     = (const float*)d_in[13];
    const float* ca_bo     = (const float*)d_in[14];
    const float* mlp_w0    = (const float*)d_in[15];
    const float* mlp_b0    = (const float*)d_in[16];
    const float* mlp_w1    = (const float*)d_in[17];
    const float* mlp_b1    = (const float*)d_in[18];
    const float* mlp_w2    = (const float*)d_in[19];
    const float* ffn_w1    = (const float*)d_in[21];
    const float* ffn_b1    = (const float*)d_in[22];
    const float* ffn_w2    = (const float*)d_in[23];
    const float* ffn_b2    = (const float*)d_in[24];
    const float* ln1_g     = (const float*)d_in[25];
    const float* ln1_b     = (const float*)d_in[26];
    const float* ln2_g     = (const float*)d_in[27];
    const float* ln2_b     = (const float*)d_in[28];
    const float* ln3_g     = (const float*)d_in[29];
    const float* ln3_b     = (const float*)d_in[30];

    char* p = (char*)d_ws;
    // weights (persist): [0, 11.5 MB)
    ushort_t* w0b   = (ushort_t*)(p + 0);          // 512x1024   1.0 MB
    ushort_t* w1b   = (ushort_t*)(p + MB(1));      // 512x512    0.5
    ushort_t* ptwb  = (ushort_t*)(p + 1572864);    // 1536x512   1.5
    ushort_t* ptob  = (ushort_t*)(p + MB(3));      // 512x512    0.5
    ushort_t* sawb  = (ushort_t*)(p + 3670016);    // 1536x512   1.5
    ushort_t* saob  = (ushort_t*)(p + MB(5));      // 512x512    0.5
    ushort_t* cawb  = (ushort_t*)(p + 5767168);    // 1536x512   1.5
    ushort_t* caob  = (ushort_t*)(p + MB(7));      // 512x512    0.5
    ushort_t* f1b   = (ushort_t*)(p + 7864320);    // 2048x512   2.0
    ushort_t* f2b   = (ushort_t*)(p + 9961472);    // 512x2048   2.0
    // activations / aliased regions (liveness-checked):
    ushort_t* memb  = (ushort_t*)(p + MB(12));     // 8192x512   8   (dies @cakv)
    ushort_t* cakvb = (ushort_t*)(p + MB(20));     // 8192x1024 16   (st2 -> attn3)
    ushort_t* tgtb  = (ushort_t*)(p + MB(36));     // 2048x512   2   (-> ptq)
    ushort_t* semb  = (ushort_t*)(p + MB(38));     // 2048x512   2   (-> Smat)
    ushort_t* Fb    = (ushort_t*)(p + MB(40));     // 2          (-> h2score)
    ushort_t* Sb    = (ushort_t*)(p + MB(42));     // 2
    float*    scores4 = (float*)(p + MB(44));      // 1
    ushort_t* relb  = (ushort_t*)(p + MB(45));     // 2          (-> ptkv)
    ushort_t* Ob    = (ushort_t*)(p + MB(47));     // 2          (attn out, reused)
    float*    x1f   = (float*)(p + MB(49));        // 4
    // aliases over dead regions:
    ushort_t* ptqb  = (ushort_t*)(p + MB(12));     // 2  over memb
    ushort_t* ptkvb = (ushort_t*)(p + MB(14));     // 4  over memb
    ushort_t* x1b   = (ushort_t*)(p + MB(18));     // 2  over memb
    ushort_t* saqkvb= (ushort_t*)(p + MB(38));     // 6  over semb/Fb/Sb
    float*    yf    = (float*)(p + MB(12));        // 4  over ptqb/ptkvb (dead)
    float*    x2f   = (float*)(p + MB(16));        // 4  over ptkvb/x1b (dead)
    ushort_t* x2b   = (ushort_t*)(p + MB(36));     // 2  over tgtb (dead)
    ushort_t* caqb  = (ushort_t*)(p + MB(44));     // 2  over scores4/relb (dead)
    float*    x3f   = (float*)(p + MB(40));        // 4  over saqkvb (dead)
    ushort_t* x3b   = (ushort_t*)(p + MB(38));     // 2  over saqkvb (dead)
    ushort_t* hb    = (ushort_t*)(p + MB(20));     // 8  over cakvb (dead)

    // ---- 1. convert everything to bf16 (one launch)
    CvtArgs ca;
    ca.src[0]  = tgt;       ca.dst[0]  = tgtb;  ca.n4[0]  = 262144;
    ca.src[1]  = semantics; ca.dst[1]  = semb;  ca.n4[1]  = 262144;
    ca.src[2]  = memory;    ca.dst[2]  = memb;  ca.n4[2]  = 1048576;
    ca.src[3]  = mlp_w0;    ca.dst[3]  = w0b;   ca.n4[3]  = 131072;
    ca.src[4]  = mlp_w1;    ca.dst[4]  = w1b;   ca.n4[4]  = 65536;
    ca.src[5]  = pt_wqkv;   ca.dst[5]  = ptwb;  ca.n4[5]  = 196608;
    ca.src[6]  = pt_wo;     ca.dst[6]  = ptob;  ca.n4[6]  = 65536;
    ca.src[7]  = sa_wqkv;   ca.dst[7]  = sawb;  ca.n4[7]  = 196608;
    ca.src[8]  = sa_wo;     ca.dst[8]  = saob;  ca.n4[8]  = 65536;
    ca.src[9]  = ca_wqkv;   ca.dst[9]  = cawb;  ca.n4[9]  = 196608;
    ca.src[10] = ca_wo;     ca.dst[10] = caob;  ca.n4[10] = 65536;
    ca.src[11] = ffn_w1;    ca.dst[11] = f1b;   ca.n4[11] = 262144;
    ca.src[12] = ffn_w2;    ca.dst[12] = f2b;   ca.n4[12] = 262144;
    megacvt_kernel<<<dim3(1024, 13), 256, 0, stream>>>(ca);

    // ---- 2. ca KV early (memb dies, frees region for aliases)
    mgemm(stream, memb, 512, cawb + 512 * 512, 512, ca_bqkv + 512, nullptr,
          nullptr, cakvb, 1024, 8192, 1024, 512, false);

    // ---- rel path
    mgemm(stream, tgtb, 512, w0b, 1024, mlp_b0, nullptr, nullptr, Fb, 512,
          2048, 512, 512, false);
    mgemm(stream, semb, 512, w0b + 512, 1024, nullptr, nullptr, nullptr, Sb, 512,
          2048, 512, 512, false);
    h2score_kernel<<<dim3(1024, 2), 512, 0, stream>>>(Fb, Sb, w1b, mlp_b1,
                                                      mlp_w2, scores4);
    softrel_kernel<<<2048, 256, 0, stream>>>(scores4, semantics, relb);

    // ---- pt attention
    mgemm(stream, tgtb, 512, ptwb, 512, pt_bqkv, nullptr, nullptr, ptqb, 512,
          2048, 512, 512, false);
    mgemm(stream, relb, 512, ptwb + 512 * 512, 512, pt_bqkv + 512, nullptr,
          nullptr, ptkvb, 1024, 2048, 1024, 512, false);
    attn2_kernel<<<512, 256, 0, stream>>>(ptqb, 512, 0, ptkvb, 1024, 0,
                                          ptkvb, 1024, 512, Ob, 64);
    mgemm(stream, Ob, 512, ptob, 512, pt_bo, tgt, x1f, x1b, 512,
          2048, 512, 512, false);

    // ---- self attention + ln1
    mgemm(stream, x1b, 512, sawb, 512, sa_bqkv, nullptr, nullptr, saqkvb, 1536,
          2048, 1536, 512, false);
    attn2_kernel<<<512, 256, 0, stream>>>(saqkvb, 1536, 0, saqkvb, 1536, 512,
                                          saqkvb, 1536, 1024, Ob, 64);
    mgemm(stream, Ob, 512, saob, 512, sa_bo, x1f, yf, nullptr, 512,
          2048, 512, 512, false);
    ln_kernel<<<512, 256, 0, stream>>>(yf, ln1_g, ln1_b, x2f, x2b);

    // ---- cross attention + ln2
    mgemm(stream, x2b, 512, cawb, 512, ca_bqkv, nullptr, nullptr, caqb, 512,
          2048, 512, 512, false);
    attn2_kernel<<<512, 256, 0, stream>>>(caqb, 512, 0, cakvb, 1024, 0,
                                          cakvb, 1024, 512, Ob, 256);
    mgemm(stream, Ob, 512, caob, 512, ca_bo, x2f, yf, nullptr, 512,
          2048, 512, 512, false);
    ln_kernel<<<512, 256, 0, stream>>>(yf, ln2_g, ln2_b, x3f, x3b);

    // ---- FFN + ln3 -> out
    mgemm(stream, x3b, 512, f1b, 512, ffn_b1, nullptr, nullptr, hb, 2048,
          2048, 2048, 512, true);
    mgemm(stream, hb, 2048, f2b, 2048, ffn_b2, x3f, yf, nullptr, 512,
          2048, 512, 2048, false);
    ln_kernel<<<512, 256, 0, stream>>>(yf, ln3_g, ln3_b, (float*)d_out, nullptr);
}

// Round 5
// 612.499 us; speedup vs baseline: 7.7534x; 1.0045x over previous
//
#include <hip/hip_runtime.h>
#include <hip/hip_bf16.h>

#define WS_B 32
#define WS_T 64
#define WS_S 64
#define WS_D 512

typedef __attribute__((ext_vector_type(8))) __bf16 bf16x8;
typedef __attribute__((ext_vector_type(4))) float f32x4;
typedef unsigned short ushort_t;

#define MB(x) ((size_t)(x) << 20)

// ---------------------------------------------------------------- helpers
__device__ __forceinline__ unsigned packpair(float lo, float hi) {
    return ((__float_as_uint(lo) + 0x8000u) >> 16) |
           ((__float_as_uint(hi) + 0x8000u) & 0xffff0000u);
}
__device__ __forceinline__ ushort_t f2bf(float x) {
    return (ushort_t)((__float_as_uint(x) + 0x8000u) >> 16);
}
__device__ __forceinline__ float bf2f(ushort_t u) {
    return __uint_as_float(((unsigned)u) << 16);
}
__device__ __forceinline__ unsigned fuse_word(unsigned f, unsigned s) {
    float lo = __uint_as_float(f << 16) + __uint_as_float(s << 16);
    float hi = __uint_as_float(f & 0xffff0000u) + __uint_as_float(s & 0xffff0000u);
    lo = fmaxf(lo, 0.f);
    hi = fmaxf(hi, 0.f);
    return packpair(lo, hi);
}
// async global->LDS, 16 B per lane; l must be wave-uniform base (lane scatters +16B)
__device__ __forceinline__ void gl2lds16(const void* g, void* l) {
    __builtin_amdgcn_global_load_lds(
        (const __attribute__((address_space(1))) void*)g,
        (__attribute__((address_space(3))) void*)l, 16, 0, 0);
}

// ---------------------------------------------------------------- mega convert
struct CvtArgs {
    const float* src[13];
    ushort_t* dst[13];
    int n4[13];
};
__global__ __launch_bounds__(256) void megacvt_kernel(CvtArgs a) {
    const int t = blockIdx.y;
    const int n = a.n4[t];
    const float4* S = (const float4*)a.src[t];
    uint2* D = (uint2*)a.dst[t];
    for (int i = blockIdx.x * 256 + threadIdx.x; i < n; i += gridDim.x * 256) {
        float4 v = S[i];
        uint2 o;
        o.x = packpair(v.x, v.y);
        o.y = packpair(v.z, v.w);
        D[i] = o;
    }
}

// ---------------------------------------------------------------- batched MFMA GEMM
// C[m,n] = act(A[m,:] . W[n,:] + bias[n]) (+ resid[m,n])
// Tile 128(M) x 256(N), 512 threads (8 waves, 2x4 wave grid, 64x64/wave).
// Staging via global_load_lds (16 B/lane, layout = tid*16 linear per buffer).
struct GemmDesc {
    const ushort_t* A;
    const ushort_t* W;
    const float* bias;
    const float* resid;
    float* C;
    ushort_t* Cb;
    int lda, ldw, ldc, K, relu, nbx, blkStart;
};
struct GemmBatch {
    GemmDesc d[4];
    int nd;
};

__global__ __launch_bounds__(512, 2) void mfma_gemm_b(GemmBatch bt) {
    __shared__ ushort_t As[128 * 32];   // 8 KB
    __shared__ ushort_t Bs[256 * 32];   // 16 KB
    int di = 0;
#pragma unroll
    for (int i = 1; i < 4; ++i)
        if (i < bt.nd && (int)blockIdx.x >= bt.d[i].blkStart) di = i;
    const GemmDesc g = bt.d[di];
    const int local = blockIdx.x - g.blkStart;
    const int mb = local / g.nbx;            // nbx may be non-pow2 (e.g. 6)
    const int nb = local - mb * g.nbx;

    const int tid = threadIdx.x;
    const int w = tid >> 6, lane = tid & 63;
    const int wm = w & 1, wn = w >> 1;
    const int l15 = lane & 15, quad = lane >> 4;

    const ushort_t* Ap  = g.A + (long)(mb * 128 + (tid >> 2)) * g.lda + (tid & 3) * 8;
    const ushort_t* Bp0 = g.W + (long)(nb * 256 + (tid >> 2)) * g.ldw + (tid & 3) * 8;
    const ushort_t* Bp1 = Bp0 + (long)128 * g.ldw;
    ushort_t* AsD  = As + w * 512;          // wave-uniform dest bases
    ushort_t* BsD0 = Bs + w * 512;
    ushort_t* BsD1 = Bs + 4096 + w * 512;

    f32x4 acc[4][4];
#pragma unroll
    for (int i = 0; i < 4; ++i)
#pragma unroll
        for (int j = 0; j < 4; ++j) acc[i][j] = (f32x4)0.f;

    for (int k0 = 0; k0 < g.K; k0 += 32) {
        __syncthreads();
        gl2lds16(Ap + k0, AsD);
        gl2lds16(Bp0 + k0, BsD0);
        gl2lds16(Bp1 + k0, BsD1);
        __syncthreads();
        bf16x8 af[4], bf[4];
#pragma unroll
        for (int mt = 0; mt < 4; ++mt)
            af[mt] = *(const bf16x8*)&As[(wm * 64 + mt * 16 + l15) * 32 + quad * 8];
#pragma unroll
        for (int nt = 0; nt < 4; ++nt)
            bf[nt] = *(const bf16x8*)&Bs[(wn * 64 + nt * 16 + l15) * 32 + quad * 8];
#pragma unroll
        for (int mt = 0; mt < 4; ++mt)
#pragma unroll
            for (int nt = 0; nt < 4; ++nt)
                acc[mt][nt] = __builtin_amdgcn_mfma_f32_16x16x32_bf16(
                    af[mt], bf[nt], acc[mt][nt], 0, 0, 0);
    }

#pragma unroll
    for (int nt = 0; nt < 4; ++nt) {
        const int col = nb * 256 + wn * 64 + nt * 16 + l15;
        const float bv = g.bias ? g.bias[col] : 0.f;
#pragma unroll
        for (int mt = 0; mt < 4; ++mt) {
            const int row0 = mb * 128 + wm * 64 + mt * 16 + quad * 4;
#pragma unroll
            for (int rg = 0; rg < 4; ++rg) {
                float v = acc[mt][nt][rg] + bv;
                if (g.relu) v = fmaxf(v, 0.f);
                const long off = (long)(row0 + rg) * g.ldc + col;
                if (g.resid) v += g.resid[off];
                if (g.C) g.C[off] = v;
                if (g.Cb) g.Cb[off] = f2bf(v);
            }
        }
    }
}

// ---------------------------------------------------------------- h2 scores (MFMA)
// A[m,k] = relu(Fb[r,k] + Sb[b*64+s,k]) built on the fly (m = r*64+s).
// B = w1 staged via global_load_lds. Epilogue folds relu(+b1)*w2, col-reduce.
__global__ __launch_bounds__(512, 2) void h2score_kernel(
    const ushort_t* __restrict__ Fb,   // (2048,512)
    const ushort_t* __restrict__ Sb,   // (2048,512) rows b*64+s
    const ushort_t* __restrict__ w1b,  // (512,512)
    const float* __restrict__ b1,
    const float* __restrict__ w2,
    float* __restrict__ scores4)       // (2, 131072)
{
    __shared__ ushort_t As[128 * 32];
    __shared__ ushort_t Bs[256 * 32];
    __shared__ float scred[128 * 4];
    const int tid = threadIdx.x;
    const int mb = blockIdx.x, nb = blockIdx.y;
    const int w = tid >> 6, lane = tid & 63;
    const int wm = w & 1, wn = w >> 1;
    const int l15 = lane & 15, quad = lane >> 4;

    const int arow = tid >> 2, akc = tid & 3;
    const int m_g = mb * 128 + arow;
    const int r = m_g >> 6, s = m_g & 63, bidx = r & 31;
    const ushort_t* Fp = Fb + (long)r * 512 + akc * 8;
    const ushort_t* Sp = Sb + (long)(bidx * 64 + s) * 512 + akc * 8;
    const ushort_t* Bp0 = w1b + (long)(nb * 256 + (tid >> 2)) * 512 + (tid & 3) * 8;
    const ushort_t* Bp1 = Bp0 + (long)128 * 512;
    ushort_t* Asw = &As[arow * 32 + akc * 8];
    ushort_t* BsD0 = Bs + w * 512;
    ushort_t* BsD1 = Bs + 4096 + w * 512;

    f32x4 acc[4][4];
#pragma unroll
    for (int i = 0; i < 4; ++i)
#pragma unroll
        for (int j = 0; j < 4; ++j) acc[i][j] = (f32x4)0.f;

    uint4 fa = *(const uint4*)(Fp);
    uint4 sa = *(const uint4*)(Sp);
    for (int k0 = 0; k0 < 512; k0 += 32) {
        __syncthreads();
        gl2lds16(Bp0 + k0, BsD0);
        gl2lds16(Bp1 + k0, BsD1);
        uint4 o;
        o.x = fuse_word(fa.x, sa.x);
        o.y = fuse_word(fa.y, sa.y);
        o.z = fuse_word(fa.z, sa.z);
        o.w = fuse_word(fa.w, sa.w);
        *(uint4*)Asw = o;
        if (k0 + 32 < 512) {
            fa = *(const uint4*)(Fp + k0 + 32);
            sa = *(const uint4*)(Sp + k0 + 32);
        }
        __syncthreads();
        bf16x8 af[4], bf[4];
#pragma unroll
        for (int mt = 0; mt < 4; ++mt)
            af[mt] = *(const bf16x8*)&As[(wm * 64 + mt * 16 + l15) * 32 + quad * 8];
#pragma unroll
        for (int nt = 0; nt < 4; ++nt)
            bf[nt] = *(const bf16x8*)&Bs[(wn * 64 + nt * 16 + l15) * 32 + quad * 8];
#pragma unroll
        for (int mt = 0; mt < 4; ++mt)
#pragma unroll
            for (int nt = 0; nt < 4; ++nt)
                acc[mt][nt] = __builtin_amdgcn_mfma_f32_16x16x32_bf16(
                    af[mt], bf[nt], acc[mt][nt], 0, 0, 0);
    }
    __syncthreads();

    float sp[4][4];
#pragma unroll
    for (int mt = 0; mt < 4; ++mt)
#pragma unroll
        for (int rg = 0; rg < 4; ++rg) sp[mt][rg] = 0.f;
#pragma unroll
    for (int nt = 0; nt < 4; ++nt) {
        const int col = nb * 256 + wn * 64 + nt * 16 + l15;
        const float cb = b1[col];
        const float cw = w2[col];
#pragma unroll
        for (int mt = 0; mt < 4; ++mt) {
#pragma unroll
            for (int rg = 0; rg < 4; ++rg)
                sp[mt][rg] += fmaxf(acc[mt][nt][rg] + cb, 0.f) * cw;
        }
    }
#pragma unroll
    for (int mt = 0; mt < 4; ++mt)
#pragma unroll
        for (int rg = 0; rg < 4; ++rg) {
            float v = sp[mt][rg];
            v += __shfl_xor(v, 1);
            v += __shfl_xor(v, 2);
            v += __shfl_xor(v, 4);
            v += __shfl_xor(v, 8);
            if (l15 == 0)
                scred[(wm * 64 + mt * 16 + quad * 4 + rg) * 4 + wn] = v;
        }
    __syncthreads();
    if (tid < 128) {
        float t = scred[tid * 4] + scred[tid * 4 + 1]
                + scred[tid * 4 + 2] + scred[tid * 4 + 3];
        scores4[(long)nb * 131072 + mb * 128 + tid] = t;
    }
}

// ---------------------------------------------------------------- softmax + weighted sum
__global__ __launch_bounds__(256) void softrel_kernel(
    const float* __restrict__ sc4,     // (2, 131072)
    const float* __restrict__ sem,     // (32, 64, 512) fp32
    ushort_t* __restrict__ rel)        // (2048, 512) bf16, rows r = t*B+b
{
    __shared__ float a_s[64];
    const int tid = threadIdx.x;
    const int r = blockIdx.x;
    const int b = r & (WS_B - 1);
    if (tid < 64) {
        float t = sc4[r * 64 + tid] + sc4[131072 + r * 64 + tid];
        float m = t;
#pragma unroll
        for (int off = 32; off > 0; off >>= 1) m = fmaxf(m, __shfl_xor(m, off));
        float e = __expf(t - m);
        float su = e;
#pragma unroll
        for (int off = 32; off > 0; off >>= 1) su += __shfl_xor(su, off);
        a_s[tid] = e / su;
    }
    __syncthreads();
#pragma unroll
    for (int dd = 0; dd < 2; ++dd) {
        const int d = tid + dd * 256;
        float accd = 0.f;
        const float* sp = sem + (long)b * 64 * 512 + d;
        for (int s = 0; s < 64; ++s)
            accd += a_s[s] * sp[s * 512];
        rel[(long)r * 512 + d] = f2bf(accd);
    }
}

// ---------------------------------------------------------------- attention v2
__global__ __launch_bounds__(256) void attn2_kernel(
    const ushort_t* __restrict__ Qm, int ldq, int qoff,
    const ushort_t* __restrict__ Km, int ldk, int koff,
    const ushort_t* __restrict__ Vm, int ldv, int voff,
    ushort_t* __restrict__ O,          // (2048,512) bf16
    int Lk)
{
    __shared__ float sQT[64 * 34];
    __shared__ float sKT[64 * 68];
    __shared__ float sS[32 * 260];
    __shared__ float sredm[8 * 34];
    __shared__ float sreds[8 * 34];
    const int tid = threadIdx.x;
    const int b  = blockIdx.x >> 4;
    const int h  = (blockIdx.x >> 1) & 7;
    const int qt = blockIdx.x & 1;
    const int L8 = Lk >> 3;

    {
        const int q = tid >> 3, c = tid & 7;
        const int qg = qt * 32 + q;
        const ushort_t* pp = Qm + (long)(qg * WS_B + b) * ldq + qoff + h * 64 + c * 8;
        uint4 u = *(const uint4*)pp;
        const ushort_t* us = (const ushort_t*)&u;
#pragma unroll
        for (int i = 0; i < 8; ++i)
            sQT[(c * 8 + i) * 34 + q] = bf2f(us[i]);
    }

    const int k4 = (tid & 15) * 4;
    const int q2 = (tid >> 4) * 2;

    for (int kt = 0; kt < Lk; kt += 64) {
        __syncthreads();
        {
            const int kk = tid >> 3, c = tid & 7;
#pragma unroll
            for (int half = 0; half < 2; ++half) {
                const int kr = kk + half * 32;
                const ushort_t* pp = Km + (long)((kt + kr) * WS_B + b) * ldk + koff + h * 64 + c * 8;
                uint4 u = *(const uint4*)pp;
                const ushort_t* us = (const ushort_t*)&u;
#pragma unroll
                for (int i = 0; i < 8; ++i)
                    sKT[(c * 8 + i) * 68 + kr] = bf2f(us[i]);
            }
        }
        __syncthreads();
        float acc[2][4] = {{0.f, 0.f, 0.f, 0.f}, {0.f, 0.f, 0.f, 0.f}};
        for (int d = 0; d < 64; ++d) {
            const float qa = sQT[d * 34 + q2];
            const float qb = sQT[d * 34 + q2 + 1];
            const float4 kv = *(const float4*)&sKT[d * 68 + k4];
            acc[0][0] += qa * kv.x; acc[0][1] += qa * kv.y;
            acc[0][2] += qa * kv.z; acc[0][3] += qa * kv.w;
            acc[1][0] += qb * kv.x; acc[1][1] += qb * kv.y;
            acc[1][2] += qb * kv.z; acc[1][3] += qb * kv.w;
        }
#pragma unroll
        for (int i = 0; i < 2; ++i) {
            float4 v;
            v.x = acc[i][0] * 0.125f; v.y = acc[i][1] * 0.125f;
            v.z = acc[i][2] * 0.125f; v.w = acc[i][3] * 0.125f;
            *(float4*)&sS[(q2 + i) * 260 + kt + k4] = v;
        }
    }
    __syncthreads();

    {
        const int q = tid & 31, part = tid >> 5;
        const int kb = part * L8;
        float m = -1e30f;
        for (int k = 0; k < L8; ++k) m = fmaxf(m, sS[q * 260 + kb + k]);
        sredm[part * 34 + q] = m;
        __syncthreads();
        float M = sredm[q];
#pragma unroll
        for (int pz = 1; pz < 8; ++pz) M = fmaxf(M, sredm[pz * 34 + q]);
        float su = 0.f;
        for (int k = 0; k < L8; ++k) {
            float e = __expf(sS[q * 260 + kb + k] - M);
            sS[q * 260 + kb + k] = e;
            su += e;
        }
        sreds[part * 34 + q] = su;
    }
    __syncthreads();

    const int d4 = (tid & 15) * 4;
    float o[2][4] = {{0.f, 0.f, 0.f, 0.f}, {0.f, 0.f, 0.f, 0.f}};
    float* sV = sKT;
    for (int kt = 0; kt < Lk; kt += 64) {
        __syncthreads();
        {
            const int kk = tid >> 3, c = tid & 7;
#pragma unroll
            for (int half = 0; half < 2; ++half) {
                const int kr = kk + half * 32;
                const ushort_t* pp = Vm + (long)((kt + kr) * WS_B + b) * ldv + voff + h * 64 + c * 8;
                uint4 u = *(const uint4*)pp;
                const ushort_t* us = (const ushort_t*)&u;
                float4 w0, w1;
                w0.x = bf2f(us[0]); w0.y = bf2f(us[1]);
                w0.z = bf2f(us[2]); w0.w = bf2f(us[3]);
                w1.x = bf2f(us[4]); w1.y = bf2f(us[5]);
                w1.z = bf2f(us[6]); w1.w = bf2f(us[7]);
                *(float4*)&sV[kr * 68 + c * 8] = w0;
                *(float4*)&sV[kr * 68 + c * 8 + 4] = w1;
            }
        }
        __syncthreads();
        for (int k = 0; k < 64; ++k) {
            const float p0 = sS[q2 * 260 + kt + k];
            const float p1 = sS[(q2 + 1) * 260 + kt + k];
            const float4 vv = *(const float4*)&sV[k * 68 + d4];
            o[0][0] += p0 * vv.x; o[0][1] += p0 * vv.y;
            o[0][2] += p0 * vv.z; o[0][3] += p0 * vv.w;
            o[1][0] += p1 * vv.x; o[1][1] += p1 * vv.y;
            o[1][2] += p1 * vv.z; o[1][3] += p1 * vv.w;
        }
    }

#pragma unroll
    for (int i = 0; i < 2; ++i) {
        float su = 0.f;
#pragma unroll
        for (int pz = 0; pz < 8; ++pz) su += sreds[pz * 34 + q2 + i];
        const float inv = 1.f / su;
        const int qg = qt * 32 + q2 + i;
        ushort_t* op = O + (long)(qg * WS_B + b) * 512 + h * 64 + d4;
        uint2 pk;
        pk.x = packpair(o[i][0] * inv, o[i][1] * inv);
        pk.y = packpair(o[i][2] * inv, o[i][3] * inv);
        *(uint2*)op = pk;
    }
}

// ---------------------------------------------------------------- layernorm (dual out)
__global__ __launch_bounds__(256) void ln_kernel(
    const float* __restrict__ X,
    const float* __restrict__ g,
    const float* __restrict__ be,
    float* __restrict__ Y,
    ushort_t* __restrict__ Yb)
{
    const int row = blockIdx.x * 4 + (threadIdx.x >> 6);
    const int lane = threadIdx.x & 63;
    const float4* xp = (const float4*)(X + (long)row * WS_D);
    float4 x0 = xp[lane], x1 = xp[lane + 64];
    float sum = x0.x + x0.y + x0.z + x0.w + x1.x + x1.y + x1.z + x1.w;
    float sq = x0.x * x0.x + x0.y * x0.y + x0.z * x0.z + x0.w * x0.w
             + x1.x * x1.x + x1.y * x1.y + x1.z * x1.z + x1.w * x1.w;
#pragma unroll
    for (int off = 32; off > 0; off >>= 1) {
        sum += __shfl_xor(sum, off);
        sq += __shfl_xor(sq, off);
    }
    const float mu = sum * (1.f / 512.f);
    const float var = sq * (1.f / 512.f) - mu * mu;
    const float rs = rsqrtf(var + 1e-5f);
    const float4* gp = (const float4*)g;
    const float4* bp = (const float4*)be;
    float4 g0 = gp[lane], g1 = gp[lane + 64], b0 = bp[lane], b1 = bp[lane + 64];
    float4 y0, y1;
    y0.x = (x0.x - mu) * rs * g0.x + b0.x;
    y0.y = (x0.y - mu) * rs * g0.y + b0.y;
    y0.z = (x0.z - mu) * rs * g0.z + b0.z;
    y0.w = (x0.w - mu) * rs * g0.w + b0.w;
    y1.x = (x1.x - mu) * rs * g1.x + b1.x;
    y1.y = (x1.y - mu) * rs * g1.y + b1.y;
    y1.z = (x1.z - mu) * rs * g1.z + b1.z;
    y1.w = (x1.w - mu) * rs * g1.w + b1.w;
    float4* yp = (float4*)(Y + (long)row * WS_D);
    yp[lane] = y0; yp[lane + 64] = y1;
    if (Yb) {
        uint2* ybp = (uint2*)(Yb + (long)row * WS_D);
        uint2 p0, p1;
        p0.x = packpair(y0.x, y0.y); p0.y = packpair(y0.z, y0.w);
        p1.x = packpair(y1.x, y1.y); p1.y = packpair(y1.z, y1.w);
        ybp[lane] = p0; ybp[lane + 64] = p1;
    }
}

// ---------------------------------------------------------------- launch helpers
static inline GemmDesc mkdesc(const ushort_t* A, int lda, const ushort_t* W, int ldw,
                              const float* bias, const float* resid, float* C,
                              ushort_t* Cb, int ldc, int N, int K, int relu,
                              int blkStart)
{
    GemmDesc d;
    d.A = A; d.W = W; d.bias = bias; d.resid = resid; d.C = C; d.Cb = Cb;
    d.lda = lda; d.ldw = ldw; d.ldc = ldc; d.K = K; d.relu = relu;
    d.nbx = N / 256;
    d.blkStart = blkStart;
    return d;
}
static inline void mgemm(hipStream_t s, const ushort_t* A, int lda,
                         const ushort_t* W, int ldw, const float* bias,
                         const float* resid, float* C, ushort_t* Cb,
                         int ldc, int M, int N, int K, bool relu)
{
    GemmBatch bt;
    bt.nd = 1;
    bt.d[0] = mkdesc(A, lda, W, ldw, bias, resid, C, Cb, ldc, N, K, relu ? 1 : 0, 0);
    bt.d[1] = bt.d[0]; bt.d[2] = bt.d[0]; bt.d[3] = bt.d[0];
    mfma_gemm_b<<<(M / 128) * (N / 256), 512, 0, s>>>(bt);
}

extern "C" void kernel_launch(void* const* d_in, const int* in_sizes, int n_in,
                              void* d_out, int out_size, void* d_ws, size_t ws_size,
                              hipStream_t stream)
{
    (void)in_sizes; (void)n_in; (void)out_size; (void)ws_size;
    const float* tgt       = (const float*)d_in[0];
    const float* memory    = (const float*)d_in[1];
    const float* semantics = (const float*)d_in[2];
    const float* pt_wqkv   = (const float*)d_in[3];
    const float* pt_bqkv   = (const float*)d_in[4];
    const float* pt_wo     = (const float*)d_in[5];
    const float* pt_bo     = (const float*)d_in[6];
    const float* sa_wqkv   = (const float*)d_in[7];
    const float* sa_bqkv   = (const float*)d_in[8];
    const float* sa_wo     = (const float*)d_in[9];
    const float* sa_bo     = (const float*)d_in[10];
    const float* ca_wqkv   = (const float*)d_in[11];
    const float* ca_bqkv   = (const float*)d_in[12];
    const float* ca_wo     = (const float*)d_in[13];
    const float* ca_bo     = (const float*)d_in[14];
    const float* mlp_w0    = (const float*)d_in[15];
    const float* mlp_b0    = (const float*)d_in[16];
    const float* mlp_w1    = (const float*)d_in[17];
    const float* mlp_b1    = (const float*)d_in[18];
    const float* mlp_w2    = (const float*)d_in[19];
    const float* ffn_w1    = (const float*)d_in[21];
    const float* ffn_b1    = (const float*)d_in[22];
    const float* ffn_w2    = (const float*)d_in[23];
    const float* ffn_b2    = (const float*)d_in[24];
    const float* ln1_g     = (const float*)d_in[25];
    const float* ln1_b     = (const float*)d_in[26];
    const float* ln2_g     = (const float*)d_in[27];
    const float* ln2_b     = (const float*)d_in[28];
    const float* ln3_g     = (const float*)d_in[29];
    const float* ln3_b     = (const float*)d_in[30];

    char* p = (char*)d_ws;
    // weights (persist): [0, 11.5 MB)
    ushort_t* w0b   = (ushort_t*)(p + 0);          // 512x1024   1.0 MB
    ushort_t* w1b   = (ushort_t*)(p + MB(1));      // 512x512    0.5
    ushort_t* ptwb  = (ushort_t*)(p + 1572864);    // 1536x512   1.5
    ushort_t* ptob  = (ushort_t*)(p + MB(3));      // 512x512    0.5
    ushort_t* sawb  = (ushort_t*)(p + 3670016);    // 1536x512   1.5
    ushort_t* saob  = (ushort_t*)(p + MB(5));      // 512x512    0.5
    ushort_t* cawb  = (ushort_t*)(p + 5767168);    // 1536x512   1.5
    ushort_t* caob  = (ushort_t*)(p + MB(7));      // 512x512    0.5
    ushort_t* f1b   = (ushort_t*)(p + 7864320);    // 2048x512   2.0
    ushort_t* f2b   = (ushort_t*)(p + 9961472);    // 512x2048   2.0
    // activations:
    ushort_t* memb  = (ushort_t*)(p + MB(12));     // 8192x512   8   (dies @cakv)
    ushort_t* cakvb = (ushort_t*)(p + MB(20));     // 8192x1024 16   (-> attn ca)
    ushort_t* tgtb  = (ushort_t*)(p + MB(36));     // 2048x512   2
    ushort_t* semb  = (ushort_t*)(p + MB(38));     // 2048x512   2
    ushort_t* Fb    = (ushort_t*)(p + MB(40));     // 2
    ushort_t* Sb    = (ushort_t*)(p + MB(42));     // 2
    float*    scores4 = (float*)(p + MB(44));      // 1
    ushort_t* relb  = (ushort_t*)(p + MB(45));     // 2
    ushort_t* Ob    = (ushort_t*)(p + MB(47));     // 2
    float*    x1f   = (float*)(p + MB(49));        // 4
    ushort_t* ptqb  = (ushort_t*)(p + MB(53));     // 2  [53,55) — NOT over memb (race!)
    // aliases over dead regions:
    ushort_t* ptkvb = (ushort_t*)(p + MB(14));     // 4  over memb (dead after cakv)
    ushort_t* x1b   = (ushort_t*)(p + MB(18));     // 2  over memb
    ushort_t* saqkvb= (ushort_t*)(p + MB(38));     // 6  over semb/Fb/Sb (dead)
    float*    yf    = (float*)(p + MB(12));        // 4  over memb head (dead)
    float*    x2f   = (float*)(p + MB(16));        // 4  over ptkvb (dead by then)
    ushort_t* x2b   = (ushort_t*)(p + MB(36));     // 2  over tgtb (dead)
    ushort_t* caqb  = (ushort_t*)(p + MB(44));     // 2  over scores4/relb (dead)
    float*    x3f   = (float*)(p + MB(40));        // 4  over saqkvb (dead)
    ushort_t* x3b   = (ushort_t*)(p + MB(38));     // 2  over saqkvb (dead)
    ushort_t* hb    = (ushort_t*)(p + MB(20));     // 8  over cakvb (dead)

    // ---- 1. convert everything to bf16 (one launch)
    CvtArgs ca;
    ca.src[0]  = tgt;       ca.dst[0]  = tgtb;  ca.n4[0]  = 262144;
    ca.src[1]  = semantics; ca.dst[1]  = semb;  ca.n4[1]  = 262144;
    ca.src[2]  = memory;    ca.dst[2]  = memb;  ca.n4[2]  = 1048576;
    ca.src[3]  = mlp_w0;    ca.dst[3]  = w0b;   ca.n4[3]  = 131072;
    ca.src[4]  = mlp_w1;    ca.dst[4]  = w1b;   ca.n4[4]  = 65536;
    ca.src[5]  = pt_wqkv;   ca.dst[5]  = ptwb;  ca.n4[5]  = 196608;
    ca.src[6]  = pt_wo;     ca.dst[6]  = ptob;  ca.n4[6]  = 65536;
    ca.src[7]  = sa_wqkv;   ca.dst[7]  = sawb;  ca.n4[7]  = 196608;
    ca.src[8]  = sa_wo;     ca.dst[8]  = saob;  ca.n4[8]  = 65536;
    ca.src[9]  = ca_wqkv;   ca.dst[9]  = cawb;  ca.n4[9]  = 196608;
    ca.src[10] = ca_wo;     ca.dst[10] = caob;  ca.n4[10] = 65536;
    ca.src[11] = ffn_w1;    ca.dst[11] = f1b;   ca.n4[11] = 262144;
    ca.src[12] = ffn_w2;    ca.dst[12] = f2b;   ca.n4[12] = 262144;
    megacvt_kernel<<<dim3(1024, 13), 256, 0, stream>>>(ca);

    // ---- 2. batched independent GEMMs: cakv (256 blk) + F (32) + Smat (32) + ptq (32)
    {
        GemmBatch bt;
        bt.nd = 4;
        bt.d[0] = mkdesc(memb, 512, cawb + 512 * 512, 512, ca_bqkv + 512, nullptr,
                         nullptr, cakvb, 1024, 1024, 512, 0, 0);
        bt.d[1] = mkdesc(tgtb, 512, w0b, 1024, mlp_b0, nullptr,
                         nullptr, Fb, 512, 512, 512, 0, 256);
        bt.d[2] = mkdesc(semb, 512, w0b + 512, 1024, nullptr, nullptr,
                         nullptr, Sb, 512, 512, 512, 0, 288);
        bt.d[3] = mkdesc(tgtb, 512, ptwb, 512, pt_bqkv, nullptr,
                         nullptr, ptqb, 512, 512, 512, 0, 320);
        mfma_gemm_b<<<352, 512, 0, stream>>>(bt);
    }

    // ---- rel path
    h2score_kernel<<<dim3(1024, 2), 512, 0, stream>>>(Fb, Sb, w1b, mlp_b1,
                                                      mlp_w2, scores4);
    softrel_kernel<<<2048, 256, 0, stream>>>(scores4, semantics, relb);

    // ---- pt attention
    mgemm(stream, relb, 512, ptwb + 512 * 512, 512, pt_bqkv + 512, nullptr,
          nullptr, ptkvb, 1024, 2048, 1024, 512, false);
    attn2_kernel<<<512, 256, 0, stream>>>(ptqb, 512, 0, ptkvb, 1024, 0,
                                          ptkvb, 1024, 512, Ob, 64);
    mgemm(stream, Ob, 512, ptob, 512, pt_bo, tgt, x1f, x1b, 512,
          2048, 512, 512, false);

    // ---- self attention + ln1
    mgemm(stream, x1b, 512, sawb, 512, sa_bqkv, nullptr, nullptr, saqkvb, 1536,
          2048, 1536, 512, false);
    attn2_kernel<<<512, 256, 0, stream>>>(saqkvb, 1536, 0, saqkvb, 1536, 512,
                                          saqkvb, 1536, 1024, Ob, 64);
    mgemm(stream, Ob, 512, saob, 512, sa_bo, x1f, yf, nullptr, 512,
          2048, 512, 512, false);
    ln_kernel<<<512, 256, 0, stream>>>(yf, ln1_g, ln1_b, x2f, x2b);

    // ---- cross attention + ln2
    mgemm(stream, x2b, 512, cawb, 512, ca_bqkv, nullptr, nullptr, caqb, 512,
          2048, 512, 512, false);
    attn2_kernel<<<512, 256, 0, stream>>>(caqb, 512, 0, cakvb, 1024, 0,
                                          cakvb, 1024, 512, Ob, 256);
    mgemm(stream, Ob, 512, caob, 512, ca_bo, x2f, yf, nullptr, 512,
          2048, 512, 512, false);
    ln_kernel<<<512, 256, 0, stream>>>(yf, ln2_g, ln2_b, x3f, x3b);

    // ---- FFN + ln3 -> out
    mgemm(stream, x3b, 512, f1b, 512, ffn_b1, nullptr, nullptr, hb, 2048,
          2048, 2048, 512, true);
    mgemm(stream, hb, 2048, f2b, 2048, ffn_b2, x3f, yf, nullptr, 512,
          2048, 512, 2048, false);
    ln_kernel<<<512, 256, 0, stream>>>(yf, ln3_g, ln3_b, (float*)d_out, nullptr);
}

// Round 6
// 527.662 us; speedup vs baseline: 9.0000x; 1.1608x over previous
//
#include <hip/hip_runtime.h>
#include <hip/hip_bf16.h>

#define WS_B 32

typedef __attribute__((ext_vector_type(8))) __bf16 bf16x8;
typedef __attribute__((ext_vector_type(4))) float f32x4;
typedef unsigned short ushort_t;

#define MB(x) ((size_t)(x) << 20)
#define LSTR 40   // LDS row stride (elems): 80 B -> bank advance 20 mod 32, max 2-way

// ---------------------------------------------------------------- helpers
__device__ __forceinline__ unsigned packpair(float lo, float hi) {
    return ((__float_as_uint(lo) + 0x8000u) >> 16) |
           ((__float_as_uint(hi) + 0x8000u) & 0xffff0000u);
}
__device__ __forceinline__ ushort_t f2bf(float x) {
    return (ushort_t)((__float_as_uint(x) + 0x8000u) >> 16);
}
__device__ __forceinline__ float bf2f(ushort_t u) {
    return __uint_as_float(((unsigned)u) << 16);
}
__device__ __forceinline__ unsigned fuse_word(unsigned f, unsigned s) {
    float lo = __uint_as_float(f << 16) + __uint_as_float(s << 16);
    float hi = __uint_as_float(f & 0xffff0000u) + __uint_as_float(s & 0xffff0000u);
    lo = fmaxf(lo, 0.f);
    hi = fmaxf(hi, 0.f);
    return packpair(lo, hi);
}

// ---------------------------------------------------------------- mega convert
struct CvtArgs {
    const float* src[13];
    ushort_t* dst[13];
    int n4[13];
};
__global__ __launch_bounds__(256) void megacvt_kernel(CvtArgs a) {
    const int t = blockIdx.y;
    const int n = a.n4[t];
    const float4* S = (const float4*)a.src[t];
    uint2* D = (uint2*)a.dst[t];
    for (int i = blockIdx.x * 256 + threadIdx.x; i < n; i += gridDim.x * 256) {
        float4 v = S[i];
        uint2 o;
        o.x = packpair(v.x, v.y);
        o.y = packpair(v.z, v.w);
        D[i] = o;
    }
}

// ---------------------------------------------------------------- batched MFMA GEMM
// Tile 128(M) x 128(N), 256 threads (4 waves, 2x2 wave grid, 64x64/wave).
// Register staging + explicit next-step prefetch (loads overlap MFMA).
struct GemmDesc {
    const ushort_t* A;
    const ushort_t* W;
    const float* bias;
    const float* resid;
    float* C;
    ushort_t* Cb;
    int lda, ldw, ldc, K, relu, nbx, blkStart;
};
struct GemmBatch {
    GemmDesc d[4];
    int nd;
};

__global__ __launch_bounds__(256, 3) void mfma_gemm2(GemmBatch bt) {
    __shared__ ushort_t As[128 * LSTR];   // 10 KB
    __shared__ ushort_t Bs[128 * LSTR];   // 10 KB
    int di = 0;
#pragma unroll
    for (int i = 1; i < 4; ++i)
        if (i < bt.nd && (int)blockIdx.x >= bt.d[i].blkStart) di = i;
    const GemmDesc g = bt.d[di];
    const int local = blockIdx.x - g.blkStart;
    const int mb = local / g.nbx;
    const int nb = local - mb * g.nbx;

    const int tid = threadIdx.x;
    const int w = tid >> 6, lane = tid & 63;
    const int wm = w & 1, wn = w >> 1;
    const int l15 = lane & 15, quad = lane >> 4;

    const int arow = tid >> 1;          // 0..127
    const int a16 = (tid & 1) * 16;     // 0 or 16
    const ushort_t* Ap = g.A + (long)(mb * 128 + arow) * g.lda + a16;
    const ushort_t* Bp = g.W + (long)(nb * 128 + arow) * g.ldw + a16;
    ushort_t* Asw = &As[arow * LSTR + a16];
    ushort_t* Bsw = &Bs[arow * LSTR + a16];

    f32x4 acc[4][4];
#pragma unroll
    for (int i = 0; i < 4; ++i)
#pragma unroll
        for (int j = 0; j < 4; ++j) acc[i][j] = (f32x4)0.f;

    uint4 a0 = *(const uint4*)Ap;
    uint4 a1 = *(const uint4*)(Ap + 8);
    uint4 b0 = *(const uint4*)Bp;
    uint4 b1 = *(const uint4*)(Bp + 8);

    for (int k0 = 0; k0 < g.K; k0 += 32) {
        __syncthreads();
        *(uint4*)Asw = a0; *(uint4*)(Asw + 8) = a1;
        *(uint4*)Bsw = b0; *(uint4*)(Bsw + 8) = b1;
        if (k0 + 32 < g.K) {
            a0 = *(const uint4*)(Ap + k0 + 32);
            a1 = *(const uint4*)(Ap + k0 + 40);
            b0 = *(const uint4*)(Bp + k0 + 32);
            b1 = *(const uint4*)(Bp + k0 + 40);
        }
        __syncthreads();
        bf16x8 af[4], bf[4];
#pragma unroll
        for (int mt = 0; mt < 4; ++mt)
            af[mt] = *(const bf16x8*)&As[(wm * 64 + mt * 16 + l15) * LSTR + quad * 8];
#pragma unroll
        for (int nt = 0; nt < 4; ++nt)
            bf[nt] = *(const bf16x8*)&Bs[(wn * 64 + nt * 16 + l15) * LSTR + quad * 8];
#pragma unroll
        for (int mt = 0; mt < 4; ++mt)
#pragma unroll
            for (int nt = 0; nt < 4; ++nt)
                acc[mt][nt] = __builtin_amdgcn_mfma_f32_16x16x32_bf16(
                    af[mt], bf[nt], acc[mt][nt], 0, 0, 0);
    }

#pragma unroll
    for (int nt = 0; nt < 4; ++nt) {
        const int col = nb * 128 + wn * 64 + nt * 16 + l15;
        const float bv = g.bias ? g.bias[col] : 0.f;
#pragma unroll
        for (int mt = 0; mt < 4; ++mt) {
            const int row0 = mb * 128 + wm * 64 + mt * 16 + quad * 4;
#pragma unroll
            for (int rg = 0; rg < 4; ++rg) {
                float v = acc[mt][nt][rg] + bv;
                if (g.relu) v = fmaxf(v, 0.f);
                const long off = (long)(row0 + rg) * g.ldc + col;
                if (g.resid) v += g.resid[off];
                if (g.C) g.C[off] = v;
                if (g.Cb) g.Cb[off] = f2bf(v);
            }
        }
    }
}

// ---------------------------------------------------------------- h2 scores (MFMA)
// Tile 128(M) x 256(N), 512 thr. A[m,k] = relu(F[r,k]+S[b*64+s,k]) on the fly.
// Register staging + prefetch; epilogue folds relu(+b1)*w2 and col-reduces.
__global__ __launch_bounds__(512, 2) void h2score_kernel(
    const ushort_t* __restrict__ Fb,   // (2048,512)
    const ushort_t* __restrict__ Sb,   // (2048,512) rows b*64+s
    const ushort_t* __restrict__ w1b,  // (512,512)
    const float* __restrict__ b1,
    const float* __restrict__ w2,
    float* __restrict__ scores4)       // (2, 131072)
{
    __shared__ ushort_t As[128 * LSTR];   // 10 KB
    __shared__ ushort_t Bs[256 * LSTR];   // 20 KB
    __shared__ float scred[128 * 4];
    const int tid = threadIdx.x;
    const int mb = blockIdx.x, nb = blockIdx.y;
    const int w = tid >> 6, lane = tid & 63;
    const int wm = w & 1, wn = w >> 1;
    const int l15 = lane & 15, quad = lane >> 4;

    const int arow = tid >> 2, akc = tid & 3;
    const int m_g = mb * 128 + arow;
    const int r = m_g >> 6, s = m_g & 63, bidx = r & 31;
    const ushort_t* Fp = Fb + (long)r * 512 + akc * 8;
    const ushort_t* Sp = Sb + (long)(bidx * 64 + s) * 512 + akc * 8;
    const ushort_t* Bp0 = w1b + (long)(nb * 256 + arow) * 512 + akc * 8;
    const ushort_t* Bp1 = Bp0 + (long)128 * 512;
    ushort_t* Asw  = &As[arow * LSTR + akc * 8];
    ushort_t* Bsw0 = &Bs[arow * LSTR + akc * 8];
    ushort_t* Bsw1 = Bsw0 + 128 * LSTR;

    f32x4 acc[4][4];
#pragma unroll
    for (int i = 0; i < 4; ++i)
#pragma unroll
        for (int j = 0; j < 4; ++j) acc[i][j] = (f32x4)0.f;

    uint4 fa = *(const uint4*)Fp;
    uint4 sa = *(const uint4*)Sp;
    uint4 bb0 = *(const uint4*)Bp0;
    uint4 bb1 = *(const uint4*)Bp1;

    for (int k0 = 0; k0 < 512; k0 += 32) {
        __syncthreads();
        uint4 o;
        o.x = fuse_word(fa.x, sa.x);
        o.y = fuse_word(fa.y, sa.y);
        o.z = fuse_word(fa.z, sa.z);
        o.w = fuse_word(fa.w, sa.w);
        *(uint4*)Asw = o;
        *(uint4*)Bsw0 = bb0;
        *(uint4*)Bsw1 = bb1;
        if (k0 + 32 < 512) {
            fa  = *(const uint4*)(Fp + k0 + 32);
            sa  = *(const uint4*)(Sp + k0 + 32);
            bb0 = *(const uint4*)(Bp0 + k0 + 32);
            bb1 = *(const uint4*)(Bp1 + k0 + 32);
        }
        __syncthreads();
        bf16x8 af[4], bf[4];
#pragma unroll
        for (int mt = 0; mt < 4; ++mt)
            af[mt] = *(const bf16x8*)&As[(wm * 64 + mt * 16 + l15) * LSTR + quad * 8];
#pragma unroll
        for (int nt = 0; nt < 4; ++nt)
            bf[nt] = *(const bf16x8*)&Bs[(wn * 64 + nt * 16 + l15) * LSTR + quad * 8];
#pragma unroll
        for (int mt = 0; mt < 4; ++mt)
#pragma unroll
            for (int nt = 0; nt < 4; ++nt)
                acc[mt][nt] = __builtin_amdgcn_mfma_f32_16x16x32_bf16(
                    af[mt], bf[nt], acc[mt][nt], 0, 0, 0);
    }
    __syncthreads();

    float sp[4][4];
#pragma unroll
    for (int mt = 0; mt < 4; ++mt)
#pragma unroll
        for (int rg = 0; rg < 4; ++rg) sp[mt][rg] = 0.f;
#pragma unroll
    for (int nt = 0; nt < 4; ++nt) {
        const int col = nb * 256 + wn * 64 + nt * 16 + l15;
        const float cb = b1[col];
        const float cw = w2[col];
#pragma unroll
        for (int mt = 0; mt < 4; ++mt) {
#pragma unroll
            for (int rg = 0; rg < 4; ++rg)
                sp[mt][rg] += fmaxf(acc[mt][nt][rg] + cb, 0.f) * cw;
        }
    }
#pragma unroll
    for (int mt = 0; mt < 4; ++mt)
#pragma unroll
        for (int rg = 0; rg < 4; ++rg) {
            float v = sp[mt][rg];
            v += __shfl_xor(v, 1);
            v += __shfl_xor(v, 2);
            v += __shfl_xor(v, 4);
            v += __shfl_xor(v, 8);
            if (l15 == 0)
                scred[(wm * 64 + mt * 16 + quad * 4 + rg) * 4 + wn] = v;
        }
    __syncthreads();
    if (tid < 128) {
        float t = scred[tid * 4] + scred[tid * 4 + 1]
                + scred[tid * 4 + 2] + scred[tid * 4 + 3];
        scores4[(long)nb * 131072 + mb * 128 + tid] = t;
    }
}

// ---------------------------------------------------------------- softmax + weighted sum
__global__ __launch_bounds__(256) void softrel_kernel(
    const float* __restrict__ sc4,     // (2, 131072)
    const ushort_t* __restrict__ semb, // (32, 64, 512) bf16
    ushort_t* __restrict__ rel)        // (2048, 512) bf16, rows r = t*B+b
{
    __shared__ float a_s[64];
    const int tid = threadIdx.x;
    const int r = blockIdx.x;
    const int b = r & (WS_B - 1);
    if (tid < 64) {
        float t = sc4[r * 64 + tid] + sc4[131072 + r * 64 + tid];
        float m = t;
#pragma unroll
        for (int off = 32; off > 0; off >>= 1) m = fmaxf(m, __shfl_xor(m, off));
        float e = __expf(t - m);
        float su = e;
#pragma unroll
        for (int off = 32; off > 0; off >>= 1) su += __shfl_xor(su, off);
        a_s[tid] = e / su;
    }
    __syncthreads();
#pragma unroll
    for (int dd = 0; dd < 2; ++dd) {
        const int d = tid + dd * 256;
        float accd = 0.f;
        const ushort_t* sp = semb + (long)b * 64 * 512 + d;
        for (int s = 0; s < 64; ++s)
            accd += a_s[s] * bf2f(sp[s * 512]);
        rel[(long)r * 512 + d] = f2bf(accd);
    }
}

// ---------------------------------------------------------------- attention v2
__global__ __launch_bounds__(256) void attn2_kernel(
    const ushort_t* __restrict__ Qm, int ldq, int qoff,
    const ushort_t* __restrict__ Km, int ldk, int koff,
    const ushort_t* __restrict__ Vm, int ldv, int voff,
    ushort_t* __restrict__ O,          // (2048,512) bf16
    int Lk)
{
    __shared__ float sQT[64 * 34];
    __shared__ float sKT[64 * 68];
    __shared__ float sS[32 * 260];
    __shared__ float sredm[8 * 34];
    __shared__ float sreds[8 * 34];
    const int tid = threadIdx.x;
    const int b  = blockIdx.x >> 4;
    const int h  = (blockIdx.x >> 1) & 7;
    const int qt = blockIdx.x & 1;
    const int L8 = Lk >> 3;

    {
        const int q = tid >> 3, c = tid & 7;
        const int qg = qt * 32 + q;
        const ushort_t* pp = Qm + (long)(qg * WS_B + b) * ldq + qoff + h * 64 + c * 8;
        uint4 u = *(const uint4*)pp;
        const ushort_t* us = (const ushort_t*)&u;
#pragma unroll
        for (int i = 0; i < 8; ++i)
            sQT[(c * 8 + i) * 34 + q] = bf2f(us[i]);
    }

    const int k4 = (tid & 15) * 4;
    const int q2 = (tid >> 4) * 2;

    for (int kt = 0; kt < Lk; kt += 64) {
        __syncthreads();
        {
            const int kk = tid >> 3, c = tid & 7;
#pragma unroll
            for (int half = 0; half < 2; ++half) {
                const int kr = kk + half * 32;
                const ushort_t* pp = Km + (long)((kt + kr) * WS_B + b) * ldk + koff + h * 64 + c * 8;
                uint4 u = *(const uint4*)pp;
                const ushort_t* us = (const ushort_t*)&u;
#pragma unroll
                for (int i = 0; i < 8; ++i)
                    sKT[(c * 8 + i) * 68 + kr] = bf2f(us[i]);
            }
        }
        __syncthreads();
        float acc[2][4] = {{0.f, 0.f, 0.f, 0.f}, {0.f, 0.f, 0.f, 0.f}};
        for (int d = 0; d < 64; ++d) {
            const float qa = sQT[d * 34 + q2];
            const float qb = sQT[d * 34 + q2 + 1];
            const float4 kv = *(const float4*)&sKT[d * 68 + k4];
            acc[0][0] += qa * kv.x; acc[0][1] += qa * kv.y;
            acc[0][2] += qa * kv.z; acc[0][3] += qa * kv.w;
            acc[1][0] += qb * kv.x; acc[1][1] += qb * kv.y;
            acc[1][2] += qb * kv.z; acc[1][3] += qb * kv.w;
        }
#pragma unroll
        for (int i = 0; i < 2; ++i) {
            float4 v;
            v.x = acc[i][0] * 0.125f; v.y = acc[i][1] * 0.125f;
            v.z = acc[i][2] * 0.125f; v.w = acc[i][3] * 0.125f;
            *(float4*)&sS[(q2 + i) * 260 + kt + k4] = v;
        }
    }
    __syncthreads();

    {
        const int q = tid & 31, part = tid >> 5;
        const int kb = part * L8;
        float m = -1e30f;
        for (int k = 0; k < L8; ++k) m = fmaxf(m, sS[q * 260 + kb + k]);
        sredm[part * 34 + q] = m;
        __syncthreads();
        float M = sredm[q];
#pragma unroll
        for (int pz = 1; pz < 8; ++pz) M = fmaxf(M, sredm[pz * 34 + q]);
        float su = 0.f;
        for (int k = 0; k < L8; ++k) {
            float e = __expf(sS[q * 260 + kb + k] - M);
            sS[q * 260 + kb + k] = e;
            su += e;
        }
        sreds[part * 34 + q] = su;
    }
    __syncthreads();

    const int d4 = (tid & 15) * 4;
    float o[2][4] = {{0.f, 0.f, 0.f, 0.f}, {0.f, 0.f, 0.f, 0.f}};
    float* sV = sKT;
    for (int kt = 0; kt < Lk; kt += 64) {
        __syncthreads();
        {
            const int kk = tid >> 3, c = tid & 7;
#pragma unroll
            for (int half = 0; half < 2; ++half) {
                const int kr = kk + half * 32;
                const ushort_t* pp = Vm + (long)((kt + kr) * WS_B + b) * ldv + voff + h * 64 + c * 8;
                uint4 u = *(const uint4*)pp;
                const ushort_t* us = (const ushort_t*)&u;
                float4 w0, w1;
                w0.x = bf2f(us[0]); w0.y = bf2f(us[1]);
                w0.z = bf2f(us[2]); w0.w = bf2f(us[3]);
                w1.x = bf2f(us[4]); w1.y = bf2f(us[5]);
                w1.z = bf2f(us[6]); w1.w = bf2f(us[7]);
                *(float4*)&sV[kr * 68 + c * 8] = w0;
                *(float4*)&sV[kr * 68 + c * 8 + 4] = w1;
            }
        }
        __syncthreads();
        for (int k = 0; k < 64; ++k) {
            const float p0 = sS[q2 * 260 + kt + k];
            const float p1 = sS[(q2 + 1) * 260 + kt + k];
            const float4 vv = *(const float4*)&sV[k * 68 + d4];
            o[0][0] += p0 * vv.x; o[0][1] += p0 * vv.y;
            o[0][2] += p0 * vv.z; o[0][3] += p0 * vv.w;
            o[1][0] += p1 * vv.x; o[1][1] += p1 * vv.y;
            o[1][2] += p1 * vv.z; o[1][3] += p1 * vv.w;
        }
    }

#pragma unroll
    for (int i = 0; i < 2; ++i) {
        float su = 0.f;
#pragma unroll
        for (int pz = 0; pz < 8; ++pz) su += sreds[pz * 34 + q2 + i];
        const float inv = 1.f / su;
        const int qg = qt * 32 + q2 + i;
        ushort_t* op = O + (long)(qg * WS_B + b) * 512 + h * 64 + d4;
        uint2 pk;
        pk.x = packpair(o[i][0] * inv, o[i][1] * inv);
        pk.y = packpair(o[i][2] * inv, o[i][3] * inv);
        *(uint2*)op = pk;
    }
}

// ---------------------------------------------------------------- layernorm (dual out)
__global__ __launch_bounds__(256) void ln_kernel(
    const float* __restrict__ X,
    const float* __restrict__ g,
    const float* __restrict__ be,
    float* __restrict__ Y,
    ushort_t* __restrict__ Yb)
{
    const int row = blockIdx.x * 4 + (threadIdx.x >> 6);
    const int lane = threadIdx.x & 63;
    const float4* xp = (const float4*)(X + (long)row * 512);
    float4 x0 = xp[lane], x1 = xp[lane + 64];
    float sum = x0.x + x0.y + x0.z + x0.w + x1.x + x1.y + x1.z + x1.w;
    float sq = x0.x * x0.x + x0.y * x0.y + x0.z * x0.z + x0.w * x0.w
             + x1.x * x1.x + x1.y * x1.y + x1.z * x1.z + x1.w * x1.w;
#pragma unroll
    for (int off = 32; off > 0; off >>= 1) {
        sum += __shfl_xor(sum, off);
        sq += __shfl_xor(sq, off);
    }
    const float mu = sum * (1.f / 512.f);
    const float var = sq * (1.f / 512.f) - mu * mu;
    const float rs = rsqrtf(var + 1e-5f);
    const float4* gp = (const float4*)g;
    const float4* bp = (const float4*)be;
    float4 g0 = gp[lane], g1 = gp[lane + 64], b0 = bp[lane], b1 = bp[lane + 64];
    float4 y0, y1;
    y0.x = (x0.x - mu) * rs * g0.x + b0.x;
    y0.y = (x0.y - mu) * rs * g0.y + b0.y;
    y0.z = (x0.z - mu) * rs * g0.z + b0.z;
    y0.w = (x0.w - mu) * rs * g0.w + b0.w;
    y1.x = (x1.x - mu) * rs * g1.x + b1.x;
    y1.y = (x1.y - mu) * rs * g1.y + b1.y;
    y1.z = (x1.z - mu) * rs * g1.z + b1.z;
    y1.w = (x1.w - mu) * rs * g1.w + b1.w;
    float4* yp = (float4*)(Y + (long)row * 512);
    yp[lane] = y0; yp[lane + 64] = y1;
    if (Yb) {
        uint2* ybp = (uint2*)(Yb + (long)row * 512);
        uint2 p0, p1;
        p0.x = packpair(y0.x, y0.y); p0.y = packpair(y0.z, y0.w);
        p1.x = packpair(y1.x, y1.y); p1.y = packpair(y1.z, y1.w);
        ybp[lane] = p0; ybp[lane + 64] = p1;
    }
}

// ---------------------------------------------------------------- launch helpers
static inline GemmDesc mkdesc(const ushort_t* A, int lda, const ushort_t* W, int ldw,
                              const float* bias, const float* resid, float* C,
                              ushort_t* Cb, int ldc, int N, int K, int relu,
                              int blkStart)
{
    GemmDesc d;
    d.A = A; d.W = W; d.bias = bias; d.resid = resid; d.C = C; d.Cb = Cb;
    d.lda = lda; d.ldw = ldw; d.ldc = ldc; d.K = K; d.relu = relu;
    d.nbx = N / 128;
    d.blkStart = blkStart;
    return d;
}
static inline void mgemm(hipStream_t s, const ushort_t* A, int lda,
                         const ushort_t* W, int ldw, const float* bias,
                         const float* resid, float* C, ushort_t* Cb,
                         int ldc, int M, int N, int K, bool relu)
{
    GemmBatch bt;
    bt.nd = 1;
    bt.d[0] = mkdesc(A, lda, W, ldw, bias, resid, C, Cb, ldc, N, K, relu ? 1 : 0, 0);
    bt.d[1] = bt.d[0]; bt.d[2] = bt.d[0]; bt.d[3] = bt.d[0];
    mfma_gemm2<<<(M / 128) * (N / 128), 256, 0, s>>>(bt);
}

extern "C" void kernel_launch(void* const* d_in, const int* in_sizes, int n_in,
                              void* d_out, int out_size, void* d_ws, size_t ws_size,
                              hipStream_t stream)
{
    (void)in_sizes; (void)n_in; (void)out_size; (void)ws_size;
    const float* tgt       = (const float*)d_in[0];
    const float* memory    = (const float*)d_in[1];
    const float* semantics = (const float*)d_in[2];
    const float* pt_wqkv   = (const float*)d_in[3];
    const float* pt_bqkv   = (const float*)d_in[4];
    const float* pt_wo     = (const float*)d_in[5];
    const float* pt_bo     = (const float*)d_in[6];
    const float* sa_wqkv   = (const float*)d_in[7];
    const float* sa_bqkv   = (const float*)d_in[8];
    const float* sa_wo     = (const float*)d_in[9];
    const float* sa_bo     = (const float*)d_in[10];
    const float* ca_wqkv   = (const float*)d_in[11];
    const float* ca_bqkv   = (const float*)d_in[12];
    const float* ca_wo     = (const float*)d_in[13];
    const float* ca_bo     = (const float*)d_in[14];
    const float* mlp_w0    = (const float*)d_in[15];
    const float* mlp_b0    = (const float*)d_in[16];
    const float* mlp_w1    = (const float*)d_in[17];
    const float* mlp_b1    = (const float*)d_in[18];
    const float* mlp_w2    = (const float*)d_in[19];
    const float* ffn_w1    = (const float*)d_in[21];
    const float* ffn_b1    = (const float*)d_in[22];
    const float* ffn_w2    = (const float*)d_in[23];
    const float* ffn_b2    = (const float*)d_in[24];
    const float* ln1_g     = (const float*)d_in[25];
    const float* ln1_b     = (const float*)d_in[26];
    const float* ln2_g     = (const float*)d_in[27];
    const float* ln2_b     = (const float*)d_in[28];
    const float* ln3_g     = (const float*)d_in[29];
    const float* ln3_b     = (const float*)d_in[30];

    char* p = (char*)d_ws;
    // weights (persist): [0, 11.5 MB)
    ushort_t* w0b   = (ushort_t*)(p + 0);          // 512x1024   1.0 MB
    ushort_t* w1b   = (ushort_t*)(p + MB(1));      // 512x512    0.5
    ushort_t* ptwb  = (ushort_t*)(p + 1572864);    // 1536x512   1.5
    ushort_t* ptob  = (ushort_t*)(p + MB(3));      // 512x512    0.5
    ushort_t* sawb  = (ushort_t*)(p + 3670016);    // 1536x512   1.5
    ushort_t* saob  = (ushort_t*)(p + MB(5));      // 512x512    0.5
    ushort_t* cawb  = (ushort_t*)(p + 5767168);    // 1536x512   1.5
    ushort_t* caob  = (ushort_t*)(p + MB(7));      // 512x512    0.5
    ushort_t* f1b   = (ushort_t*)(p + 7864320);    // 2048x512   2.0
    ushort_t* f2b   = (ushort_t*)(p + 9961472);    // 512x2048   2.0
    // activations:
    ushort_t* memb  = (ushort_t*)(p + MB(12));     // 8192x512   8   (dies @cakv)
    ushort_t* cakvb = (ushort_t*)(p + MB(20));     // 8192x1024 16   (-> attn ca)
    ushort_t* tgtb  = (ushort_t*)(p + MB(36));     // 2048x512   2
    ushort_t* semb  = (ushort_t*)(p + MB(38));     // 2048x512   2
    ushort_t* Fb    = (ushort_t*)(p + MB(40));     // 2
    ushort_t* Sb    = (ushort_t*)(p + MB(42));     // 2
    float*    scores4 = (float*)(p + MB(44));      // 1
    ushort_t* relb  = (ushort_t*)(p + MB(45));     // 2
    ushort_t* Ob    = (ushort_t*)(p + MB(47));     // 2
    float*    x1f   = (float*)(p + MB(49));        // 4
    ushort_t* ptqb  = (ushort_t*)(p + MB(53));     // 2  [53,55) — NOT over memb
    // aliases over dead regions:
    ushort_t* ptkvb = (ushort_t*)(p + MB(14));     // 4  over memb (dead after cakv)
    ushort_t* x1b   = (ushort_t*)(p + MB(18));     // 2  over memb
    ushort_t* saqkvb= (ushort_t*)(p + MB(38));     // 6  over semb/Fb/Sb (dead)
    float*    yf    = (float*)(p + MB(12));        // 4  over memb head (dead)
    float*    x2f   = (float*)(p + MB(16));        // 4  over ptkvb (dead by then)
    ushort_t* x2b   = (ushort_t*)(p + MB(36));     // 2  over tgtb (dead)
    ushort_t* caqb  = (ushort_t*)(p + MB(44));     // 2  over scores4/relb (dead)
    float*    x3f   = (float*)(p + MB(40));        // 4  over saqkvb (dead)
    ushort_t* x3b   = (ushort_t*)(p + MB(38));     // 2  over saqkvb (dead)
    ushort_t* hb    = (ushort_t*)(p + MB(20));     // 8  over cakvb (dead)

    // ---- 1. convert everything to bf16 (one launch)
    CvtArgs ca;
    ca.src[0]  = tgt;       ca.dst[0]  = tgtb;  ca.n4[0]  = 262144;
    ca.src[1]  = semantics; ca.dst[1]  = semb;  ca.n4[1]  = 262144;
    ca.src[2]  = memory;    ca.dst[2]  = memb;  ca.n4[2]  = 1048576;
    ca.src[3]  = mlp_w0;    ca.dst[3]  = w0b;   ca.n4[3]  = 131072;
    ca.src[4]  = mlp_w1;    ca.dst[4]  = w1b;   ca.n4[4]  = 65536;
    ca.src[5]  = pt_wqkv;   ca.dst[5]  = ptwb;  ca.n4[5]  = 196608;
    ca.src[6]  = pt_wo;     ca.dst[6]  = ptob;  ca.n4[6]  = 65536;
    ca.src[7]  = sa_wqkv;   ca.dst[7]  = sawb;  ca.n4[7]  = 196608;
    ca.src[8]  = sa_wo;     ca.dst[8]  = saob;  ca.n4[8]  = 65536;
    ca.src[9]  = ca_wqkv;   ca.dst[9]  = cawb;  ca.n4[9]  = 196608;
    ca.src[10] = ca_wo;     ca.dst[10] = caob;  ca.n4[10] = 65536;
    ca.src[11] = ffn_w1;    ca.dst[11] = f1b;   ca.n4[11] = 262144;
    ca.src[12] = ffn_w2;    ca.dst[12] = f2b;   ca.n4[12] = 262144;
    megacvt_kernel<<<dim3(1024, 13), 256, 0, stream>>>(ca);

    // ---- 2. batched independent GEMMs: cakv(512) + F(64) + Smat(64) + ptq(64)
    {
        GemmBatch bt;
        bt.nd = 4;
        bt.d[0] = mkdesc(memb, 512, cawb + 512 * 512, 512, ca_bqkv + 512, nullptr,
                         nullptr, cakvb, 1024, 1024, 512, 0, 0);
        bt.d[1] = mkdesc(tgtb, 512, w0b, 1024, mlp_b0, nullptr,
                         nullptr, Fb, 512, 512, 512, 0, 512);
        bt.d[2] = mkdesc(semb, 512, w0b + 512, 1024, nullptr, nullptr,
                         nullptr, Sb, 512, 512, 512, 0, 576);
        bt.d[3] = mkdesc(tgtb, 512, ptwb, 512, pt_bqkv, nullptr,
                         nullptr, ptqb, 512, 512, 512, 0, 640);
        mfma_gemm2<<<704, 256, 0, stream>>>(bt);
    }

    // ---- rel path
    h2score_kernel<<<dim3(1024, 2), 512, 0, stream>>>(Fb, Sb, w1b, mlp_b1,
                                                      mlp_w2, scores4);
    softrel_kernel<<<2048, 256, 0, stream>>>(scores4, semb, relb);

    // ---- pt attention
    mgemm(stream, relb, 512, ptwb + 512 * 512, 512, pt_bqkv + 512, nullptr,
          nullptr, ptkvb, 1024, 2048, 1024, 512, false);
    attn2_kernel<<<512, 256, 0, stream>>>(ptqb, 512, 0, ptkvb, 1024, 0,
                                          ptkvb, 1024, 512, Ob, 64);
    mgemm(stream, Ob, 512, ptob, 512, pt_bo, tgt, x1f, x1b, 512,
          2048, 512, 512, false);

    // ---- self attention + ln1
    mgemm(stream, x1b, 512, sawb, 512, sa_bqkv, nullptr, nullptr, saqkvb, 1536,
          2048, 1536, 512, false);
    attn2_kernel<<<512, 256, 0, stream>>>(saqkvb, 1536, 0, saqkvb, 1536, 512,
                                          saqkvb, 1536, 1024, Ob, 64);
    mgemm(stream, Ob, 512, saob, 512, sa_bo, x1f, yf, nullptr, 512,
          2048, 512, 512, false);
    ln_kernel<<<512, 256, 0, stream>>>(yf, ln1_g, ln1_b, x2f, x2b);

    // ---- cross attention + ln2
    mgemm(stream, x2b, 512, cawb, 512, ca_bqkv, nullptr, nullptr, caqb, 512,
          2048, 512, 512, false);
    attn2_kernel<<<512, 256, 0, stream>>>(caqb, 512, 0, cakvb, 1024, 0,
                                          cakvb, 1024, 512, Ob, 256);
    mgemm(stream, Ob, 512, caob, 512, ca_bo, x2f, yf, nullptr, 512,
          2048, 512, 512, false);
    ln_kernel<<<512, 256, 0, stream>>>(yf, ln2_g, ln2_b, x3f, x3b);

    // ---- FFN + ln3 -> out
    mgemm(stream, x3b, 512, f1b, 512, ffn_b1, nullptr, nullptr, hb, 2048,
          2048, 2048, 512, true);
    mgemm(stream, hb, 2048, f2b, 2048, ffn_b2, x3f, yf, nullptr, 512,
          2048, 512, 2048, false);
    ln_kernel<<<512, 256, 0, stream>>>(yf, ln3_g, ln3_b, (float*)d_out, nullptr);
}